// Round 2
// baseline (1235.804 us; speedup 1.0000x reference)
//
#include <hip/hip_runtime.h>
#include <hip/hip_bf16.h>

#define IN_DIM 128
#define HH 8
#define DD 16
#define HD 128  // H*D

// ---------------------------------------------------------------------------
// Kernel 0: dtype sniff.  View h as uint16.  If the underlying storage is
// bf16, even-indexed uint16s are bf16 values of N(0,1) samples -> exponent
// field in a sane range ~always.  If storage is fp32, even-indexed uint16s
// are the LOW mantissa bits of floats -> exponent field ~uniform random ->
// sane only ~12% of the time.  64 samples, threshold 40: decisive.
// flag = 1 -> fp32 storage, 0 -> bf16 storage.
// ---------------------------------------------------------------------------
__global__ void sniff_kernel(const unsigned short* __restrict__ h_raw,
                             int* __restrict__ flag) {
  if (threadIdx.x == 0 && blockIdx.x == 0) {
    int sane = 0;
    for (int i = 0; i < 128; i += 2) {
      const unsigned short u = h_raw[i];
      const int expo = (u >> 7) & 0xFF;
      if (expo >= 112 && expo <= 143) sane++;  // |x| in [2^-15, 2^16)
    }
    *flag = (sane >= 40) ? 0 : 1;
  }
}

// ---------------------------------------------------------------------------
// Kernel 1: fused Q/K/V projection.  One block (128 threads) per node.
// h row staged in LDS; thread j computes output channel j for Q, K, V.
// Dual load paths selected by the wave-uniform dtype flag.
// ---------------------------------------------------------------------------
__global__ __launch_bounds__(128) void proj_kernel(
    const void* __restrict__ h,
    const void* __restrict__ Wq, const void* __restrict__ bq,
    const void* __restrict__ Wk, const void* __restrict__ bk,
    const void* __restrict__ Wv, const void* __restrict__ bv,
    float* __restrict__ Qf, float* __restrict__ Kf, float* __restrict__ Vf,
    const int* __restrict__ flag, int n_nodes) {
  __shared__ float hs[IN_DIM];
  const int n = blockIdx.x;
  const int j = threadIdx.x;
  if (n >= n_nodes) return;
  const int isf = *flag;

  float q, k, v;
  if (isf) {
    const float* hp = (const float*)h;
    hs[j] = hp[(size_t)n * IN_DIM + j];
    __syncthreads();
    const float* wqp = (const float*)Wq;
    const float* wkp = (const float*)Wk;
    const float* wvp = (const float*)Wv;
    q = ((const float*)bq)[j];
    k = ((const float*)bk)[j];
    v = ((const float*)bv)[j];
#pragma unroll 8
    for (int i = 0; i < IN_DIM; ++i) {
      const float hv = hs[i];
      q += hv * wqp[i * HD + j];
      k += hv * wkp[i * HD + j];
      v += hv * wvp[i * HD + j];
    }
  } else {
    const __hip_bfloat16* hp = (const __hip_bfloat16*)h;
    hs[j] = __bfloat162float(hp[(size_t)n * IN_DIM + j]);
    __syncthreads();
    const __hip_bfloat16* wqp = (const __hip_bfloat16*)Wq;
    const __hip_bfloat16* wkp = (const __hip_bfloat16*)Wk;
    const __hip_bfloat16* wvp = (const __hip_bfloat16*)Wv;
    q = __bfloat162float(((const __hip_bfloat16*)bq)[j]);
    k = __bfloat162float(((const __hip_bfloat16*)bk)[j]);
    v = __bfloat162float(((const __hip_bfloat16*)bv)[j]);
#pragma unroll 8
    for (int i = 0; i < IN_DIM; ++i) {
      const float hv = hs[i];
      q += hv * __bfloat162float(wqp[i * HD + j]);
      k += hv * __bfloat162float(wkp[i * HD + j]);
      v += hv * __bfloat162float(wvp[i * HD + j]);
    }
  }
  const size_t o = (size_t)n * HD + j;
  Qf[o] = q;
  Kf[o] = k;
  Vf[o] = v;
}

// ---------------------------------------------------------------------------
// Kernel 2: per-edge attention score + scatter.  128 threads per edge
// (one per channel, 16 lanes per head -> shuffle-reduce dot product).
// ---------------------------------------------------------------------------
__global__ __launch_bounds__(256) void edge_kernel(
    const int* __restrict__ src, const int* __restrict__ dst,
    const float* __restrict__ Qf, const float* __restrict__ Kf,
    const float* __restrict__ Vf,
    float* __restrict__ wV, float* __restrict__ z, int n_edges) {
  const int t = blockIdx.x * blockDim.x + threadIdx.x;
  const int e = t >> 7;      // edge index (128 threads / edge)
  const int c = t & 127;     // channel = head*16 + d
  if (e >= n_edges) return;

  const int s = src[e];
  const int d = dst[e];

  const size_t so = (size_t)s * HD + c;
  const size_t dofs = (size_t)d * HD + c;

  float kq = Kf[so] * Qf[dofs];
  // reduce across the 16 lanes of this head (stays inside one wave)
  kq += __shfl_xor(kq, 1, 64);
  kq += __shfl_xor(kq, 2, 64);
  kq += __shfl_xor(kq, 4, 64);
  kq += __shfl_xor(kq, 8, 64);

  const float score = __expf(fminf(fmaxf(kq * 0.25f, -5.0f), 5.0f));

  atomicAdd(&wV[dofs], Vf[so] * score);
  if ((c & 15) == 0) {
    atomicAdd(&z[(size_t)d * HH + (c >> 4)], score);
  }
}

// ---------------------------------------------------------------------------
// Kernel 3: normalize and store (dtype per flag).
// ---------------------------------------------------------------------------
__global__ __launch_bounds__(256) void norm_kernel(
    const float* __restrict__ wV, const float* __restrict__ z,
    void* __restrict__ out, const int* __restrict__ flag, int n_nodes) {
  const int t = blockIdx.x * blockDim.x + threadIdx.x;
  if (t >= n_nodes * HD) return;
  const int n = t >> 7;
  const int c = t & 127;
  const float denom = z[(size_t)n * HH + (c >> 4)] + 1e-6f;
  const float r = wV[t] / denom;
  if (*flag) {
    ((float*)out)[t] = r;
  } else {
    ((__hip_bfloat16*)out)[t] = __float2bfloat16(r);
  }
}

// ---------------------------------------------------------------------------
extern "C" void kernel_launch(void* const* d_in, const int* in_sizes, int n_in,
                              void* d_out, int out_size, void* d_ws, size_t ws_size,
                              hipStream_t stream) {
  const void* h  = d_in[0];
  const void* Wq = d_in[1];
  const void* bq = d_in[2];
  const void* Wk = d_in[3];
  const void* bk = d_in[4];
  const void* Wv = d_in[5];
  const void* bv = d_in[6];
  const int* src = (const int*)d_in[7];
  const int* dst = (const int*)d_in[8];

  const int n_nodes = in_sizes[0] / IN_DIM;   // 50000
  const int n_edges = in_sizes[7];            // 1600000

  // workspace layout: flag (256B slot) | Qf | Kf | Vf | wV | z   (all fp32)
  int* flag = (int*)d_ws;
  float* Qf = (float*)((char*)d_ws + 256);
  float* Kf = Qf + (size_t)n_nodes * HD;
  float* Vf = Kf + (size_t)n_nodes * HD;
  float* wV = Vf + (size_t)n_nodes * HD;
  float* z  = wV + (size_t)n_nodes * HD;

  sniff_kernel<<<1, 64, 0, stream>>>((const unsigned short*)h, flag);

  // zero the accumulators (wV and z are contiguous)
  hipMemsetAsync(wV, 0, ((size_t)n_nodes * HD + (size_t)n_nodes * HH) * sizeof(float),
                 stream);

  proj_kernel<<<n_nodes, 128, 0, stream>>>(h, Wq, bq, Wk, bk, Wv, bv,
                                           Qf, Kf, Vf, flag, n_nodes);

  const long long edge_threads = (long long)n_edges * HD;
  const int eb = 256;
  edge_kernel<<<(int)((edge_threads + eb - 1) / eb), eb, 0, stream>>>(
      src, dst, Qf, Kf, Vf, wV, z, n_edges);

  const int nt = n_nodes * HD;
  norm_kernel<<<(nt + 255) / 256, 256, 0, stream>>>(wV, z, d_out, flag, n_nodes);
}

// Round 3
// 810.096 us; speedup vs baseline: 1.5255x; 1.5255x over previous
//
#include <hip/hip_runtime.h>
#include <hip/hip_bf16.h>

#define IN_DIM 128
#define HH 8
#define DD 16
#define HD 128  // H*D
#define SCAN_B 256

// ---------------------------------------------------------------------------
// Kernel 0: dtype sniff (unchanged from round 2 — it worked).
// flag = 1 -> fp32 storage, 0 -> bf16 storage.
// ---------------------------------------------------------------------------
__global__ void sniff_kernel(const unsigned short* __restrict__ h_raw,
                             int* __restrict__ flag) {
  if (threadIdx.x == 0 && blockIdx.x == 0) {
    int sane = 0;
    for (int i = 0; i < 128; i += 2) {
      const unsigned short u = h_raw[i];
      const int expo = (u >> 7) & 0xFF;
      if (expo >= 112 && expo <= 143) sane++;
    }
    *flag = (sane >= 40) ? 0 : 1;
  }
}

// ---------------------------------------------------------------------------
// Kernel 1: fused Q/K/V projection.  Q -> fp32; K,V -> bf16 (halves the
// gather-phase read traffic; inputs were bf16 so the extra rounding is
// ~2^-9 relative).
// ---------------------------------------------------------------------------
__global__ __launch_bounds__(128) void proj_kernel(
    const void* __restrict__ h,
    const void* __restrict__ Wq, const void* __restrict__ bq,
    const void* __restrict__ Wk, const void* __restrict__ bk,
    const void* __restrict__ Wv, const void* __restrict__ bv,
    float* __restrict__ Qf, __hip_bfloat16* __restrict__ Kb,
    __hip_bfloat16* __restrict__ Vb,
    const int* __restrict__ flag, int n_nodes) {
  __shared__ float hs[IN_DIM];
  const int n = blockIdx.x;
  const int j = threadIdx.x;
  if (n >= n_nodes) return;
  const int isf = *flag;

  float q, k, v;
  if (isf) {
    const float* hp = (const float*)h;
    hs[j] = hp[(size_t)n * IN_DIM + j];
    __syncthreads();
    const float* wqp = (const float*)Wq;
    const float* wkp = (const float*)Wk;
    const float* wvp = (const float*)Wv;
    q = ((const float*)bq)[j];
    k = ((const float*)bk)[j];
    v = ((const float*)bv)[j];
#pragma unroll 8
    for (int i = 0; i < IN_DIM; ++i) {
      const float hv = hs[i];
      q += hv * wqp[i * HD + j];
      k += hv * wkp[i * HD + j];
      v += hv * wvp[i * HD + j];
    }
  } else {
    const __hip_bfloat16* hp = (const __hip_bfloat16*)h;
    hs[j] = __bfloat162float(hp[(size_t)n * IN_DIM + j]);
    __syncthreads();
    const __hip_bfloat16* wqp = (const __hip_bfloat16*)Wq;
    const __hip_bfloat16* wkp = (const __hip_bfloat16*)Wk;
    const __hip_bfloat16* wvp = (const __hip_bfloat16*)Wv;
    q = __bfloat162float(((const __hip_bfloat16*)bq)[j]);
    k = __bfloat162float(((const __hip_bfloat16*)bk)[j]);
    v = __bfloat162float(((const __hip_bfloat16*)bv)[j]);
#pragma unroll 8
    for (int i = 0; i < IN_DIM; ++i) {
      const float hv = hs[i];
      q += hv * __bfloat162float(wqp[i * HD + j]);
      k += hv * __bfloat162float(wkp[i * HD + j]);
      v += hv * __bfloat162float(wvp[i * HD + j]);
    }
  }
  const size_t o = (size_t)n * HD + j;
  Qf[o] = q;
  Kb[o] = __float2bfloat16(k);
  Vb[o] = __float2bfloat16(v);
}

// ---------------------------------------------------------------------------
// CSR build: histogram -> 2-level exclusive scan -> scatter src by dst.
// ---------------------------------------------------------------------------
__global__ __launch_bounds__(256) void hist_kernel(
    const int* __restrict__ dst, int* __restrict__ cnt, int n_edges) {
  const int e = blockIdx.x * blockDim.x + threadIdx.x;
  if (e < n_edges) atomicAdd(&cnt[dst[e]], 1);
}

// per-block exclusive scan over chunks of SCAN_B; writes exclusive-within-
// block to exs[] and the block total to bsum[].
__global__ __launch_bounds__(SCAN_B) void scan1_kernel(
    const int* __restrict__ cnt, int* __restrict__ exs,
    int* __restrict__ bsum, int n) {
  __shared__ int sh[SCAN_B];
  const int t = threadIdx.x;
  const int i = blockIdx.x * SCAN_B + t;
  int v = (i < n) ? cnt[i] : 0;
  sh[t] = v;
  __syncthreads();
  // Hillis-Steele inclusive scan
  for (int off = 1; off < SCAN_B; off <<= 1) {
    int add = (t >= off) ? sh[t - off] : 0;
    __syncthreads();
    sh[t] += add;
    __syncthreads();
  }
  if (i < n) exs[i] = sh[t] - v;  // exclusive
  if (t == SCAN_B - 1) bsum[blockIdx.x] = sh[t];
}

__global__ void scan2_kernel(int* __restrict__ bsum, int nb) {
  if (threadIdx.x == 0 && blockIdx.x == 0) {
    int run = 0;
    for (int b = 0; b < nb; ++b) {
      int v = bsum[b];
      bsum[b] = run;
      run += v;
    }
  }
}

__global__ __launch_bounds__(SCAN_B) void scan3_kernel(
    const int* __restrict__ exs, const int* __restrict__ bsum,
    int* __restrict__ row_ptr, int* __restrict__ cursor,
    int n, int n_edges) {
  const int i = blockIdx.x * SCAN_B + threadIdx.x;
  if (i < n) {
    const int v = exs[i] + bsum[blockIdx.x];
    row_ptr[i] = v;
    cursor[i] = v;
  }
  if (i == 0) row_ptr[n] = n_edges;
}

__global__ __launch_bounds__(256) void scatter_kernel(
    const int* __restrict__ src, const int* __restrict__ dst,
    int* __restrict__ cursor, int* __restrict__ edge_src, int n_edges) {
  const int e = blockIdx.x * blockDim.x + threadIdx.x;
  if (e < n_edges) {
    const int pos = atomicAdd(&cursor[dst[e]], 1);
    edge_src[pos] = src[e];
  }
}

// ---------------------------------------------------------------------------
// Kernel 2: per-destination gather.  One block of 128 threads per dst node.
// Thread c owns channel c (head = c>>4).  Q[dst] in registers; loop over
// incoming edges reading K/V rows (bf16, 256B each, coalesced), 16-lane
// shuffle dot, accumulate score*V and z in registers, write final
// normalized output once.  Zero fp atomics.
// ---------------------------------------------------------------------------
__global__ __launch_bounds__(128) void gather_kernel(
    const int* __restrict__ row_ptr, const int* __restrict__ edge_src,
    const float* __restrict__ Qf, const __hip_bfloat16* __restrict__ Kb,
    const __hip_bfloat16* __restrict__ Vb,
    void* __restrict__ out, const int* __restrict__ flag, int n_nodes) {
  const int d = blockIdx.x;
  const int c = threadIdx.x;
  if (d >= n_nodes) return;

  const float qc = Qf[(size_t)d * HD + c];
  const int start = row_ptr[d];
  const int end = row_ptr[d + 1];

  float accV = 0.0f, accZ = 0.0f;

  int s_next = (start < end) ? edge_src[start] : 0;
  for (int i = start; i < end; ++i) {
    const int s = s_next;
    if (i + 1 < end) s_next = edge_src[i + 1];
    const size_t so = (size_t)s * HD + c;
    const float kc = __bfloat162float(Kb[so]);
    const float vc = __bfloat162float(Vb[so]);

    float kq = kc * qc;
    kq += __shfl_xor(kq, 1, 64);
    kq += __shfl_xor(kq, 2, 64);
    kq += __shfl_xor(kq, 4, 64);
    kq += __shfl_xor(kq, 8, 64);

    const float score = __expf(fminf(fmaxf(kq * 0.25f, -5.0f), 5.0f));
    accV += score * vc;
    accZ += score;
  }

  const float r = accV / (accZ + 1e-6f);
  const size_t o = (size_t)d * HD + c;
  if (*flag) {
    ((float*)out)[o] = r;
  } else {
    ((__hip_bfloat16*)out)[o] = __float2bfloat16(r);
  }
}

// ---------------------------------------------------------------------------
extern "C" void kernel_launch(void* const* d_in, const int* in_sizes, int n_in,
                              void* d_out, int out_size, void* d_ws, size_t ws_size,
                              hipStream_t stream) {
  const void* h  = d_in[0];
  const void* Wq = d_in[1];
  const void* bq = d_in[2];
  const void* Wk = d_in[3];
  const void* bk = d_in[4];
  const void* Wv = d_in[5];
  const void* bv = d_in[6];
  const int* src = (const int*)d_in[7];
  const int* dst = (const int*)d_in[8];

  const int n_nodes = in_sizes[0] / IN_DIM;   // 50000
  const int n_edges = in_sizes[7];            // 1600000
  const int nb = (n_nodes + SCAN_B - 1) / SCAN_B;

  // workspace layout
  char* p = (char*)d_ws;
  int* flag = (int*)p;                 p += 256;
  float* Qf = (float*)p;               p += (size_t)n_nodes * HD * 4;
  __hip_bfloat16* Kb = (__hip_bfloat16*)p;  p += (size_t)n_nodes * HD * 2;
  __hip_bfloat16* Vb = (__hip_bfloat16*)p;  p += (size_t)n_nodes * HD * 2;
  int* cnt = (int*)p;                  p += (size_t)n_nodes * 4;
  int* exs = (int*)p;                  p += (size_t)n_nodes * 4;
  int* bsum = (int*)p;                 p += (size_t)(nb + 1) * 4;
  int* row_ptr = (int*)p;              p += (size_t)(n_nodes + 1) * 4;
  int* cursor = (int*)p;               p += (size_t)n_nodes * 4;
  int* edge_src = (int*)p;             p += (size_t)n_edges * 4;

  sniff_kernel<<<1, 64, 0, stream>>>((const unsigned short*)h, flag);

  hipMemsetAsync(cnt, 0, (size_t)n_nodes * sizeof(int), stream);

  proj_kernel<<<n_nodes, 128, 0, stream>>>(h, Wq, bq, Wk, bk, Wv, bv,
                                           Qf, Kb, Vb, flag, n_nodes);

  const int eb = 256;
  const int egrid = (n_edges + eb - 1) / eb;
  hist_kernel<<<egrid, eb, 0, stream>>>(dst, cnt, n_edges);
  scan1_kernel<<<nb, SCAN_B, 0, stream>>>(cnt, exs, bsum, n_nodes);
  scan2_kernel<<<1, 64, 0, stream>>>(bsum, nb);
  scan3_kernel<<<nb, SCAN_B, 0, stream>>>(exs, bsum, row_ptr, cursor,
                                          n_nodes, n_edges);
  scatter_kernel<<<egrid, eb, 0, stream>>>(src, dst, cursor, edge_src, n_edges);

  gather_kernel<<<n_nodes, 128, 0, stream>>>(row_ptr, edge_src, Qf, Kb, Vb,
                                             d_out, flag, n_nodes);
}

// Round 4
// 570.405 us; speedup vs baseline: 2.1665x; 1.4202x over previous
//
#include <hip/hip_runtime.h>
#include <hip/hip_bf16.h>

#define IN_DIM 128
#define HH 8
#define DD 16
#define HD 128   // H*D
#define SCAN_B 256

#define MT  64   // nodes per proj block
#define KP  136  // padded K stride (bf16 elems); 272 B rows = 17*16, keeps
                 // ds_read_b128 16B-aligned and bank aliasing at free 2-way
#define NCH 128  // output-channel chunk staged in LDS (= one of Q/K/V)

typedef float f32x4 __attribute__((ext_vector_type(4)));
typedef short s16x8 __attribute__((ext_vector_type(8)));

// ---------------------------------------------------------------------------
// Kernel 0: dtype sniff.  flag = 1 -> fp32 storage, 0 -> bf16 storage.
// (Round-2 evidence: fp32 on this harness, but keep it self-discriminating.)
// ---------------------------------------------------------------------------
__global__ void sniff_kernel(const unsigned short* __restrict__ h_raw,
                             int* __restrict__ flag) {
  if (threadIdx.x == 0 && blockIdx.x == 0) {
    int sane = 0;
    for (int i = 0; i < 128; i += 2) {
      const unsigned short u = h_raw[i];
      const int expo = (u >> 7) & 0xFF;
      if (expo >= 112 && expo <= 143) sane++;
    }
    *flag = (sane >= 40) ? 0 : 1;
  }
}

// ---------------------------------------------------------------------------
// Kernel 1: W^T staging.  Wt[n][k] bf16, n in [0,384) = Q|K|V columns,
// padded row stride KP.  One block per n, thread k.  Reads are strided but
// W is tiny (192 KB fp32) and L2-resident; writes coalesced.
// ---------------------------------------------------------------------------
__global__ __launch_bounds__(128) void wt_kernel(
    const void* __restrict__ Wq, const void* __restrict__ Wk,
    const void* __restrict__ Wv, __hip_bfloat16* __restrict__ Wt,
    const int* __restrict__ flag) {
  const int n = blockIdx.x;   // 0..383
  const int k = threadIdx.x;  // 0..127
  const int mat = n >> 7;
  const int col = n & 127;
  const void* W = (mat == 0) ? Wq : (mat == 1) ? Wk : Wv;
  float v;
  if (*flag) v = ((const float*)W)[(size_t)k * HD + col];
  else       v = __bfloat162float(((const __hip_bfloat16*)W)[(size_t)k * HD + col]);
  Wt[(size_t)n * KP + k] = __float2bfloat16(v);
}

// ---------------------------------------------------------------------------
// Kernel 2: MFMA projection.  [N x 128] @ [128 x 384] + bias.
// Block: 256 threads (4 waves), M-tile 64 nodes.  A (h tile, bf16) in LDS;
// B staged per 128-col chunk (exactly one of Q/K/V).  Each wave owns one
// 16-node m-subtile and 8 n-tiles of 16; K-loop = 4 MFMAs/tile.
// Outputs: Q fp32 -> Qf; K,V bf16 packed into KVp dwords (K low, V high).
// ---------------------------------------------------------------------------
__global__ __launch_bounds__(256) void proj_kernel(
    const void* __restrict__ h, const __hip_bfloat16* __restrict__ Wt,
    const void* __restrict__ bq, const void* __restrict__ bk,
    const void* __restrict__ bv,
    float* __restrict__ Qf, unsigned int* __restrict__ KVp,
    const int* __restrict__ flag, int n_nodes) {
  __shared__ short Bs[NCH * KP];  // 34816 B
  __shared__ short As[MT * KP];   // 17408 B  (total 52224 B -> 3 blocks/CU)

  const int tid = threadIdx.x;
  const int node0 = blockIdx.x * MT;
  const int isf = *flag;

  // ---- stage A: 64 nodes x 128 ch as bf16 pairs (dword LDS writes) ----
#pragma unroll
  for (int j = 0; j < 16; ++j) {
    const int pid = tid + j * 256;  // pair id 0..4095
    const int m = pid >> 6;         // node within tile
    const int kk = (pid & 63) * 2;  // channel pair
    const int g = node0 + m;
    unsigned int pack = 0;
    if (g < n_nodes) {
      if (isf) {
        const float* hp = (const float*)h + (size_t)g * HD + kk;
        const float f0 = hp[0], f1 = hp[1];
        const __hip_bfloat16 b0 = __float2bfloat16(f0);
        const __hip_bfloat16 b1 = __float2bfloat16(f1);
        pack = (unsigned int)(*(const unsigned short*)&b0) |
               ((unsigned int)(*(const unsigned short*)&b1) << 16);
      } else {
        pack = *(const unsigned int*)((const __hip_bfloat16*)h +
                                      (size_t)g * HD + kk);
      }
    }
    *(unsigned int*)&As[m * KP + kk] = pack;
  }
  __syncthreads();

  const int wave = tid >> 6;   // m-subtile
  const int lane = tid & 63;
  const int l15 = lane & 15;
  const int quad = lane >> 4;

  // A fragments for this wave's 16 nodes, all 4 k-steps (held in VGPRs)
  s16x8 afrag[4];
#pragma unroll
  for (int k4 = 0; k4 < 4; ++k4)
    afrag[k4] = *(const s16x8*)&As[(wave * 16 + l15) * KP + k4 * 32 + quad * 8];

  for (int c = 0; c < 3; ++c) {
    __syncthreads();  // Bs reuse guard
    // ---- stage Bs: 128 Wt rows (34816 B linear), uint4 copy ----
    const uint4* gsrc = (const uint4*)(Wt + (size_t)c * NCH * KP);
    for (int j = tid; j < (NCH * KP * 2) / 16; j += 256)
      ((uint4*)Bs)[j] = gsrc[j];
    __syncthreads();

    f32x4 acc[8];
#pragma unroll
    for (int t = 0; t < 8; ++t) acc[t] = (f32x4){0.f, 0.f, 0.f, 0.f};

#pragma unroll
    for (int t = 0; t < 8; ++t) {
#pragma unroll
      for (int k4 = 0; k4 < 4; ++k4) {
        const s16x8 bfrag =
            *(const s16x8*)&Bs[(t * 16 + l15) * KP + k4 * 32 + quad * 8];
        acc[t] = __builtin_amdgcn_mfma_f32_16x16x32_bf16(afrag[k4], bfrag,
                                                         acc[t], 0, 0, 0);
      }
    }

    // ---- epilogue: bias + store ----
    const void* bp = (c == 0) ? bq : (c == 1) ? bk : bv;
#pragma unroll
    for (int t = 0; t < 8; ++t) {
      const int ncol = t * 16 + l15;  // channel within this matrix
      const float bias = isf ? ((const float*)bp)[ncol]
                             : __bfloat162float(((const __hip_bfloat16*)bp)[ncol]);
#pragma unroll
      for (int r = 0; r < 4; ++r) {
        const int g = node0 + wave * 16 + quad * 4 + r;
        if (g < n_nodes) {
          const float val = acc[t][r] + bias;
          if (c == 0) {
            Qf[(size_t)g * HD + ncol] = val;
          } else {
            const __hip_bfloat16 b = __float2bfloat16(val);
            unsigned short* kv = (unsigned short*)&KVp[(size_t)g * HD + ncol];
            kv[c - 1] = *(const unsigned short*)&b;  // c==1: K low, c==2: V high
          }
        }
      }
    }
  }
}

// ---------------------------------------------------------------------------
// CSR build: histogram -> scan (parallel carry) -> scatter src by dst.
// ---------------------------------------------------------------------------
__global__ __launch_bounds__(256) void hist_kernel(
    const int* __restrict__ dst, int* __restrict__ cnt, int n_edges) {
  const int e = blockIdx.x * blockDim.x + threadIdx.x;
  if (e < n_edges) atomicAdd(&cnt[dst[e]], 1);
}

__global__ __launch_bounds__(SCAN_B) void scan1_kernel(
    const int* __restrict__ cnt, int* __restrict__ exs,
    int* __restrict__ bsum, int n) {
  __shared__ int sh[SCAN_B];
  const int t = threadIdx.x;
  const int i = blockIdx.x * SCAN_B + t;
  int v = (i < n) ? cnt[i] : 0;
  sh[t] = v;
  __syncthreads();
  for (int off = 1; off < SCAN_B; off <<= 1) {
    int add = (t >= off) ? sh[t - off] : 0;
    __syncthreads();
    sh[t] += add;
    __syncthreads();
  }
  if (i < n) exs[i] = sh[t] - v;
  if (t == SCAN_B - 1) bsum[blockIdx.x] = sh[t];
}

// single-block parallel exclusive scan of block sums (nb <= SCAN_B fast path)
__global__ __launch_bounds__(SCAN_B) void scan2_kernel(int* __restrict__ bsum,
                                                       int nb) {
  __shared__ int sh[SCAN_B];
  const int t = threadIdx.x;
  if (nb <= SCAN_B) {
    int v = (t < nb) ? bsum[t] : 0;
    sh[t] = v;
    __syncthreads();
    for (int off = 1; off < SCAN_B; off <<= 1) {
      int add = (t >= off) ? sh[t - off] : 0;
      __syncthreads();
      sh[t] += add;
      __syncthreads();
    }
    if (t < nb) bsum[t] = sh[t] - v;
  } else if (t == 0) {
    int run = 0;
    for (int b = 0; b < nb; ++b) { int v = bsum[b]; bsum[b] = run; run += v; }
  }
}

__global__ __launch_bounds__(SCAN_B) void scan3_kernel(
    const int* __restrict__ exs, const int* __restrict__ bsum,
    int* __restrict__ row_ptr, int* __restrict__ cursor, int n, int n_edges) {
  const int i = blockIdx.x * SCAN_B + threadIdx.x;
  if (i < n) {
    const int v = exs[i] + bsum[blockIdx.x];
    row_ptr[i] = v;
    cursor[i] = v;
  }
  if (i == 0) row_ptr[n] = n_edges;
}

__global__ __launch_bounds__(256) void scatter_kernel(
    const int* __restrict__ src, const int* __restrict__ dst,
    int* __restrict__ cursor, int* __restrict__ edge_src, int n_edges) {
  const int e = blockIdx.x * blockDim.x + threadIdx.x;
  if (e < n_edges) {
    const int pos = atomicAdd(&cursor[dst[e]], 1);
    edge_src[pos] = src[e];
  }
}

// ---------------------------------------------------------------------------
// Kernel 3: per-destination gather.  One 128-thread block per dst node.
// KV packed: one dword per edge-channel (K low ushort, V high), 2-deep
// software pipeline on the KV loads.  Zero fp atomics.
// ---------------------------------------------------------------------------
__global__ __launch_bounds__(128) void gather_kernel(
    const int* __restrict__ row_ptr, const int* __restrict__ edge_src,
    const float* __restrict__ Qf, const unsigned int* __restrict__ KVp,
    void* __restrict__ out, const int* __restrict__ flag, int n_nodes) {
  const int d = blockIdx.x;
  const int c = threadIdx.x;
  if (d >= n_nodes) return;

  const float qc = Qf[(size_t)d * HD + c];
  const int start = row_ptr[d];
  const int deg = row_ptr[d + 1] - start;

  float accV = 0.0f, accZ = 0.0f;
  int s1 = (deg > 1) ? edge_src[start + 1] : 0;
  unsigned int kv0 = (deg > 0) ? KVp[(size_t)edge_src[start] * HD + c] : 0u;
  unsigned int kv1 = (deg > 1) ? KVp[(size_t)s1 * HD + c] : 0u;

  for (int i = 0; i < deg; ++i) {
    unsigned int kv2 = 0u;
    if (i + 2 < deg) {
      const int s2 = edge_src[start + i + 2];
      kv2 = KVp[(size_t)s2 * HD + c];  // issued 2 iterations ahead
    }
    const float kc = __uint_as_float(kv0 << 16);
    const float vc = __uint_as_float(kv0 & 0xFFFF0000u);
    float kq = kc * qc;
    kq += __shfl_xor(kq, 1, 64);
    kq += __shfl_xor(kq, 2, 64);
    kq += __shfl_xor(kq, 4, 64);
    kq += __shfl_xor(kq, 8, 64);
    const float score = __expf(fminf(fmaxf(kq * 0.25f, -5.0f), 5.0f));
    accV += score * vc;
    accZ += score;
    kv0 = kv1;
    kv1 = kv2;
  }

  const float r = accV / (accZ + 1e-6f);
  const size_t o = (size_t)d * HD + c;
  if (*flag) ((float*)out)[o] = r;
  else       ((__hip_bfloat16*)out)[o] = __float2bfloat16(r);
}

// ---------------------------------------------------------------------------
extern "C" void kernel_launch(void* const* d_in, const int* in_sizes, int n_in,
                              void* d_out, int out_size, void* d_ws, size_t ws_size,
                              hipStream_t stream) {
  const void* h  = d_in[0];
  const void* Wq = d_in[1];
  const void* bq = d_in[2];
  const void* Wk = d_in[3];
  const void* bk = d_in[4];
  const void* Wv = d_in[5];
  const void* bv = d_in[6];
  const int* src = (const int*)d_in[7];
  const int* dst = (const int*)d_in[8];

  const int n_nodes = in_sizes[0] / IN_DIM;  // 50000
  const int n_edges = in_sizes[7];           // 1600000
  const int nb = (n_nodes + SCAN_B - 1) / SCAN_B;

  // workspace layout (all offsets 256B-aligned)
  char* p = (char*)d_ws;
  int* flag = (int*)p;                       p += 256;
  float* Qf = (float*)p;                     p += (size_t)n_nodes * HD * 4;
  unsigned int* KVp = (unsigned int*)p;      p += (size_t)n_nodes * HD * 4;
  __hip_bfloat16* Wt = (__hip_bfloat16*)p;   p += ((size_t)384 * KP * 2 + 255) / 256 * 256;
  int* cnt = (int*)p;                        p += (size_t)n_nodes * 4;
  int* exs = (int*)p;                        p += (size_t)n_nodes * 4;
  int* bsum = (int*)p;                       p += (size_t)(nb + 1) * 4;
  int* row_ptr = (int*)p;                    p += (size_t)(n_nodes + 1) * 4;
  int* cursor = (int*)p;                     p += (size_t)n_nodes * 4;
  int* edge_src = (int*)p;                   p += (size_t)n_edges * 4;

  sniff_kernel<<<1, 64, 0, stream>>>((const unsigned short*)h, flag);
  hipMemsetAsync(cnt, 0, (size_t)n_nodes * sizeof(int), stream);

  wt_kernel<<<384, 128, 0, stream>>>(Wq, Wk, Wv, Wt, flag);

  const int pgrid = (n_nodes + MT - 1) / MT;
  proj_kernel<<<pgrid, 256, 0, stream>>>(h, Wt, bq, bk, bv, Qf, KVp, flag,
                                         n_nodes);

  const int eb = 256;
  const int egrid = (n_edges + eb - 1) / eb;
  hist_kernel<<<egrid, eb, 0, stream>>>(dst, cnt, n_edges);
  scan1_kernel<<<nb, SCAN_B, 0, stream>>>(cnt, exs, bsum, n_nodes);
  scan2_kernel<<<1, SCAN_B, 0, stream>>>(bsum, nb);
  scan3_kernel<<<nb, SCAN_B, 0, stream>>>(exs, bsum, row_ptr, cursor,
                                          n_nodes, n_edges);
  scatter_kernel<<<egrid, eb, 0, stream>>>(src, dst, cursor, edge_src, n_edges);

  gather_kernel<<<n_nodes, 128, 0, stream>>>(row_ptr, edge_src, Qf, KVp,
                                             d_out, flag, n_nodes);
}

// Round 5
// 465.877 us; speedup vs baseline: 2.6526x; 1.2244x over previous
//
#include <hip/hip_runtime.h>
#include <hip/hip_bf16.h>

#define IN_DIM 128
#define HH 8
#define DD 16
#define HD 128   // H*D
#define SCAN_B 256

#define MT  64   // nodes per proj block
#define KP  136  // padded K stride for Wt (bf16 elems)
#define NCH 128  // output-channel chunk staged in LDS (= one of Q/K/V)

typedef float f32x4 __attribute__((ext_vector_type(4)));
typedef short s16x8 __attribute__((ext_vector_type(8)));

// ---------------------------------------------------------------------------
// Kernel 0: dtype sniff.  flag = 1 -> fp32 storage, 0 -> bf16 storage.
// ---------------------------------------------------------------------------
__global__ void sniff_kernel(const unsigned short* __restrict__ h_raw,
                             int* __restrict__ flag) {
  if (threadIdx.x == 0 && blockIdx.x == 0) {
    int sane = 0;
    for (int i = 0; i < 128; i += 2) {
      const unsigned short u = h_raw[i];
      const int expo = (u >> 7) & 0xFF;
      if (expo >= 112 && expo <= 143) sane++;
    }
    *flag = (sane >= 40) ? 0 : 1;
  }
}

// ---------------------------------------------------------------------------
// Kernel 1: W^T staging.  Wt[n][k] bf16, n in [0,384), padded stride KP.
// ---------------------------------------------------------------------------
__global__ __launch_bounds__(128) void wt_kernel(
    const void* __restrict__ Wq, const void* __restrict__ Wk,
    const void* __restrict__ Wv, __hip_bfloat16* __restrict__ Wt,
    const int* __restrict__ flag) {
  const int n = blockIdx.x;   // 0..383
  const int k = threadIdx.x;  // 0..127
  const int mat = n >> 7;
  const int col = n & 127;
  const void* W = (mat == 0) ? Wq : (mat == 1) ? Wk : Wv;
  float v;
  if (*flag) v = ((const float*)W)[(size_t)k * HD + col];
  else       v = __bfloat162float(((const __hip_bfloat16*)W)[(size_t)k * HD + col]);
  Wt[(size_t)n * KP + k] = __float2bfloat16(v);
}

// ---------------------------------------------------------------------------
// Kernel 2: MFMA projection.  [N x 128] @ [128 x 384] + bias.
// Outputs: Q fp32 -> Qf; K, V bf16 -> separate contiguous rows (gather
// reads K rows 32B/lane in the score stage, V rows 2B/lane in the V stage).
// ---------------------------------------------------------------------------
__global__ __launch_bounds__(256) void proj_kernel(
    const void* __restrict__ h, const __hip_bfloat16* __restrict__ Wt,
    const void* __restrict__ bq, const void* __restrict__ bk,
    const void* __restrict__ bv,
    float* __restrict__ Qf, __hip_bfloat16* __restrict__ Kb,
    __hip_bfloat16* __restrict__ Vb,
    const int* __restrict__ flag, int n_nodes) {
  __shared__ short Bs[NCH * KP];  // 34816 B
  __shared__ short As[MT * KP];   // 17408 B

  const int tid = threadIdx.x;
  const int node0 = blockIdx.x * MT;
  const int isf = *flag;

  // ---- stage A: 64 nodes x 128 ch as bf16 pairs ----
#pragma unroll
  for (int j = 0; j < 16; ++j) {
    const int pid = tid + j * 256;
    const int m = pid >> 6;
    const int kk = (pid & 63) * 2;
    const int g = node0 + m;
    unsigned int pack = 0;
    if (g < n_nodes) {
      if (isf) {
        const float* hp = (const float*)h + (size_t)g * HD + kk;
        const float f0 = hp[0], f1 = hp[1];
        const __hip_bfloat16 b0 = __float2bfloat16(f0);
        const __hip_bfloat16 b1 = __float2bfloat16(f1);
        pack = (unsigned int)(*(const unsigned short*)&b0) |
               ((unsigned int)(*(const unsigned short*)&b1) << 16);
      } else {
        pack = *(const unsigned int*)((const __hip_bfloat16*)h +
                                      (size_t)g * HD + kk);
      }
    }
    *(unsigned int*)&As[m * KP + kk] = pack;
  }
  __syncthreads();

  const int wave = tid >> 6;
  const int lane = tid & 63;
  const int l15 = lane & 15;
  const int quad = lane >> 4;

  s16x8 afrag[4];
#pragma unroll
  for (int k4 = 0; k4 < 4; ++k4)
    afrag[k4] = *(const s16x8*)&As[(wave * 16 + l15) * KP + k4 * 32 + quad * 8];

  for (int c = 0; c < 3; ++c) {
    __syncthreads();
    const uint4* gsrc = (const uint4*)(Wt + (size_t)c * NCH * KP);
    for (int j = tid; j < (NCH * KP * 2) / 16; j += 256)
      ((uint4*)Bs)[j] = gsrc[j];
    __syncthreads();

    f32x4 acc[8];
#pragma unroll
    for (int t = 0; t < 8; ++t) acc[t] = (f32x4){0.f, 0.f, 0.f, 0.f};

#pragma unroll
    for (int t = 0; t < 8; ++t) {
#pragma unroll
      for (int k4 = 0; k4 < 4; ++k4) {
        const s16x8 bfrag =
            *(const s16x8*)&Bs[(t * 16 + l15) * KP + k4 * 32 + quad * 8];
        acc[t] = __builtin_amdgcn_mfma_f32_16x16x32_bf16(afrag[k4], bfrag,
                                                         acc[t], 0, 0, 0);
      }
    }

    const void* bp = (c == 0) ? bq : (c == 1) ? bk : bv;
#pragma unroll
    for (int t = 0; t < 8; ++t) {
      const int ncol = t * 16 + l15;
      const float bias = isf ? ((const float*)bp)[ncol]
                             : __bfloat162float(((const __hip_bfloat16*)bp)[ncol]);
#pragma unroll
      for (int r = 0; r < 4; ++r) {
        const int g = node0 + wave * 16 + quad * 4 + r;
        if (g < n_nodes) {
          const float val = acc[t][r] + bias;
          const size_t o = (size_t)g * HD + ncol;
          if (c == 0)      Qf[o] = val;
          else if (c == 1) Kb[o] = __float2bfloat16(val);
          else             Vb[o] = __float2bfloat16(val);
        }
      }
    }
  }
}

// ---------------------------------------------------------------------------
// CSR build: histogram -> scan -> scatter src by dst.
// ---------------------------------------------------------------------------
__global__ __launch_bounds__(256) void hist_kernel(
    const int* __restrict__ dst, int* __restrict__ cnt, int n_edges) {
  const int e = blockIdx.x * blockDim.x + threadIdx.x;
  if (e < n_edges) atomicAdd(&cnt[dst[e]], 1);
}

__global__ __launch_bounds__(SCAN_B) void scan1_kernel(
    const int* __restrict__ cnt, int* __restrict__ exs,
    int* __restrict__ bsum, int n) {
  __shared__ int sh[SCAN_B];
  const int t = threadIdx.x;
  const int i = blockIdx.x * SCAN_B + t;
  int v = (i < n) ? cnt[i] : 0;
  sh[t] = v;
  __syncthreads();
  for (int off = 1; off < SCAN_B; off <<= 1) {
    int add = (t >= off) ? sh[t - off] : 0;
    __syncthreads();
    sh[t] += add;
    __syncthreads();
  }
  if (i < n) exs[i] = sh[t] - v;
  if (t == SCAN_B - 1) bsum[blockIdx.x] = sh[t];
}

__global__ __launch_bounds__(SCAN_B) void scan2_kernel(int* __restrict__ bsum,
                                                       int nb) {
  __shared__ int sh[SCAN_B];
  const int t = threadIdx.x;
  if (nb <= SCAN_B) {
    int v = (t < nb) ? bsum[t] : 0;
    sh[t] = v;
    __syncthreads();
    for (int off = 1; off < SCAN_B; off <<= 1) {
      int add = (t >= off) ? sh[t - off] : 0;
      __syncthreads();
      sh[t] += add;
      __syncthreads();
    }
    if (t < nb) bsum[t] = sh[t] - v;
  } else if (t == 0) {
    int run = 0;
    for (int b = 0; b < nb; ++b) { int v = bsum[b]; bsum[b] = run; run += v; }
  }
}

__global__ __launch_bounds__(SCAN_B) void scan3_kernel(
    const int* __restrict__ exs, const int* __restrict__ bsum,
    int* __restrict__ row_ptr, int* __restrict__ cursor, int n, int n_edges) {
  const int i = blockIdx.x * SCAN_B + threadIdx.x;
  if (i < n) {
    const int v = exs[i] + bsum[blockIdx.x];
    row_ptr[i] = v;
    cursor[i] = v;
  }
  if (i == 0) row_ptr[n] = n_edges;
}

__global__ __launch_bounds__(256) void scatter_kernel(
    const int* __restrict__ src, const int* __restrict__ dst,
    int* __restrict__ cursor, int* __restrict__ edge_src, int n_edges) {
  const int e = blockIdx.x * blockDim.x + threadIdx.x;
  if (e < n_edges) {
    const int pos = atomicAdd(&cursor[dst[e]], 1);
    edge_src[pos] = src[e];
  }
}

// ---------------------------------------------------------------------------
// Kernel 3: per-destination gather, two-phase per 16-edge group.
//   Score stage: thread = (edge 0..15, head 0..7).  Q slice (16 ch, x0.25)
//     in registers; K row slice = 2x16B coalesced loads; 16 FMAs; ONE exp
//     per (edge,head).  No shuffles.
//   V stage: thread = channel.  Scores broadcast from LDS (same-address
//     ds_read), one bf16 V load + FMA per edge.
// Double-buffered score tile -> one barrier per group.
// ---------------------------------------------------------------------------
__global__ __launch_bounds__(128) void gather_kernel(
    const int* __restrict__ row_ptr, const int* __restrict__ edge_src,
    const float* __restrict__ Qf, const __hip_bfloat16* __restrict__ Kb,
    const __hip_bfloat16* __restrict__ Vb,
    void* __restrict__ out, const int* __restrict__ flag, int n_nodes) {
  __shared__ float sc[2][16 * HH];  // scores [edge][head]
  __shared__ int   ss[2][16];       // src ids

  const int d = blockIdx.x;
  const int tid = threadIdx.x;

  // score-stage role
  const int eloc = tid >> 3;   // 0..15
  const int hh8  = tid & 7;    // 0..7
  // V-stage role
  const int hd16 = tid >> 4;   // head for channel tid

  const int start = row_ptr[d];
  const int deg = row_ptr[d + 1] - start;

  // preload this thread's Q slice, pre-scaled by 1/sqrt(D)=0.25
  float qreg[16];
  {
    const f32x4* qp = (const f32x4*)(Qf + (size_t)d * HD + hh8 * 16);
#pragma unroll
    for (int j = 0; j < 4; ++j) {
      const f32x4 q4 = qp[j];
      qreg[j * 4 + 0] = q4[0] * 0.25f;
      qreg[j * 4 + 1] = q4[1] * 0.25f;
      qreg[j * 4 + 2] = q4[2] * 0.25f;
      qreg[j * 4 + 3] = q4[3] * 0.25f;
    }
  }

  float accV = 0.0f, accZ = 0.0f;
  const int ngroups = (deg + 15) >> 4;

  for (int g = 0; g < ngroups; ++g) {
    const int buf = g & 1;
    const int ei = g * 16 + eloc;

    float score = 0.0f;
    int s = 0;
    if (ei < deg) {
      s = edge_src[start + ei];
      const uint4* kp = (const uint4*)(Kb + (size_t)s * HD + hh8 * 16);
      unsigned int kw[8];
      *(uint4*)&kw[0] = kp[0];
      *(uint4*)&kw[4] = kp[1];
      float dot = 0.0f;
#pragma unroll
      for (int i = 0; i < 8; ++i) {
        const float klo = __uint_as_float(kw[i] << 16);
        const float khi = __uint_as_float(kw[i] & 0xFFFF0000u);
        dot = fmaf(qreg[2 * i], klo, dot);
        dot = fmaf(qreg[2 * i + 1], khi, dot);
      }
      score = __expf(fminf(fmaxf(dot, -5.0f), 5.0f));
    }
    sc[buf][eloc * HH + hh8] = score;
    if (hh8 == 0) ss[buf][eloc] = s;
    __syncthreads();

    const int lim = (deg - g * 16 < 16) ? (deg - g * 16) : 16;
    if (lim == 16) {
#pragma unroll
      for (int e = 0; e < 16; ++e) {
        const int s2 = ss[buf][e];
        const float sco = sc[buf][e * HH + hd16];
        const unsigned short vu = *(const unsigned short*)(Vb + (size_t)s2 * HD + tid);
        const float v = __uint_as_float(((unsigned int)vu) << 16);
        accV = fmaf(sco, v, accV);
        accZ += sco;
      }
    } else {
      for (int e = 0; e < lim; ++e) {
        const int s2 = ss[buf][e];
        const float sco = sc[buf][e * HH + hd16];
        const unsigned short vu = *(const unsigned short*)(Vb + (size_t)s2 * HD + tid);
        const float v = __uint_as_float(((unsigned int)vu) << 16);
        accV = fmaf(sco, v, accV);
        accZ += sco;
      }
    }
  }

  const float r = accV / (accZ + 1e-6f);
  const size_t o = (size_t)d * HD + tid;
  if (*flag) ((float*)out)[o] = r;
  else       ((__hip_bfloat16*)out)[o] = __float2bfloat16(r);
}

// ---------------------------------------------------------------------------
extern "C" void kernel_launch(void* const* d_in, const int* in_sizes, int n_in,
                              void* d_out, int out_size, void* d_ws, size_t ws_size,
                              hipStream_t stream) {
  const void* h  = d_in[0];
  const void* Wq = d_in[1];
  const void* bq = d_in[2];
  const void* Wk = d_in[3];
  const void* bk = d_in[4];
  const void* Wv = d_in[5];
  const void* bv = d_in[6];
  const int* src = (const int*)d_in[7];
  const int* dst = (const int*)d_in[8];

  const int n_nodes = in_sizes[0] / IN_DIM;  // 50000
  const int n_edges = in_sizes[7];           // 1600000
  const int nb = (n_nodes + SCAN_B - 1) / SCAN_B;

  // workspace layout (256B-aligned chunks)
  char* p = (char*)d_ws;
  int* flag = (int*)p;                       p += 256;
  float* Qf = (float*)p;                     p += (size_t)n_nodes * HD * 4;
  __hip_bfloat16* Kb = (__hip_bfloat16*)p;   p += (size_t)n_nodes * HD * 2;
  __hip_bfloat16* Vb = (__hip_bfloat16*)p;   p += (size_t)n_nodes * HD * 2;
  __hip_bfloat16* Wt = (__hip_bfloat16*)p;   p += ((size_t)384 * KP * 2 + 255) / 256 * 256;
  int* cnt = (int*)p;                        p += (size_t)n_nodes * 4;
  int* exs = (int*)p;                        p += (size_t)n_nodes * 4;
  int* bsum = (int*)p;                       p += (size_t)(nb + 1) * 4;
  int* row_ptr = (int*)p;                    p += (size_t)(n_nodes + 1) * 4;
  int* cursor = (int*)p;                     p += (size_t)n_nodes * 4;
  int* edge_src = (int*)p;                   p += (size_t)n_edges * 4;

  sniff_kernel<<<1, 64, 0, stream>>>((const unsigned short*)h, flag);
  hipMemsetAsync(cnt, 0, (size_t)n_nodes * sizeof(int), stream);

  wt_kernel<<<384, 128, 0, stream>>>(Wq, Wk, Wv, Wt, flag);

  const int pgrid = (n_nodes + MT - 1) / MT;
  proj_kernel<<<pgrid, 256, 0, stream>>>(h, Wt, bq, bk, bv, Qf, Kb, Vb, flag,
                                         n_nodes);

  const int eb = 256;
  const int egrid = (n_edges + eb - 1) / eb;
  hist_kernel<<<egrid, eb, 0, stream>>>(dst, cnt, n_edges);
  scan1_kernel<<<nb, SCAN_B, 0, stream>>>(cnt, exs, bsum, n_nodes);
  scan2_kernel<<<1, SCAN_B, 0, stream>>>(bsum, nb);
  scan3_kernel<<<nb, SCAN_B, 0, stream>>>(exs, bsum, row_ptr, cursor,
                                          n_nodes, n_edges);
  scatter_kernel<<<egrid, eb, 0, stream>>>(src, dst, cursor, edge_src, n_edges);

  gather_kernel<<<n_nodes, 128, 0, stream>>>(row_ptr, edge_src, Qf, Kb, Vb,
                                             d_out, flag, n_nodes);
}

// Round 6
// 341.898 us; speedup vs baseline: 3.6145x; 1.3626x over previous
//
#include <hip/hip_runtime.h>
#include <hip/hip_bf16.h>

#define IN_DIM 128
#define HH 8
#define DD 16
#define HD 128   // H*D
#define SCAN_B 256
#define CHUNK 8192  // edges per bucketize block

#define MT  64   // nodes per proj block
#define KP  136  // padded K stride for Wt (bf16 elems)
#define NCH 128  // output-channel chunk staged in LDS

typedef float f32x4 __attribute__((ext_vector_type(4)));
typedef short s16x8 __attribute__((ext_vector_type(8)));

// ---------------------------------------------------------------------------
// Kernel 0: dtype sniff.  flag = 1 -> fp32 storage, 0 -> bf16 storage.
// ---------------------------------------------------------------------------
__global__ void sniff_kernel(const unsigned short* __restrict__ h_raw,
                             int* __restrict__ flag) {
  if (threadIdx.x == 0 && blockIdx.x == 0) {
    int sane = 0;
    for (int i = 0; i < 128; i += 2) {
      const unsigned short u = h_raw[i];
      const int expo = (u >> 7) & 0xFF;
      if (expo >= 112 && expo <= 143) sane++;
    }
    *flag = (sane >= 40) ? 0 : 1;
  }
}

// ---------------------------------------------------------------------------
// Kernel 1: W^T staging.  Wt[n][k] bf16, n in [0,384), padded stride KP.
// ---------------------------------------------------------------------------
__global__ __launch_bounds__(128) void wt_kernel(
    const void* __restrict__ Wq, const void* __restrict__ Wk,
    const void* __restrict__ Wv, __hip_bfloat16* __restrict__ Wt,
    const int* __restrict__ flag) {
  const int n = blockIdx.x;
  const int k = threadIdx.x;
  const int mat = n >> 7;
  const int col = n & 127;
  const void* W = (mat == 0) ? Wq : (mat == 1) ? Wk : Wv;
  float v;
  if (*flag) v = ((const float*)W)[(size_t)k * HD + col];
  else       v = __bfloat162float(((const __hip_bfloat16*)W)[(size_t)k * HD + col]);
  Wt[(size_t)n * KP + k] = __float2bfloat16(v);
}

// ---------------------------------------------------------------------------
// Kernel 2: MFMA projection.  [N x 128] @ [128 x 384] + bias.
// ---------------------------------------------------------------------------
__global__ __launch_bounds__(256) void proj_kernel(
    const void* __restrict__ h, const __hip_bfloat16* __restrict__ Wt,
    const void* __restrict__ bq, const void* __restrict__ bk,
    const void* __restrict__ bv,
    float* __restrict__ Qf, __hip_bfloat16* __restrict__ Kb,
    __hip_bfloat16* __restrict__ Vb,
    const int* __restrict__ flag, int n_nodes) {
  __shared__ short Bs[NCH * KP];
  __shared__ short As[MT * KP];

  const int tid = threadIdx.x;
  const int node0 = blockIdx.x * MT;
  const int isf = *flag;

#pragma unroll
  for (int j = 0; j < 16; ++j) {
    const int pid = tid + j * 256;
    const int m = pid >> 6;
    const int kk = (pid & 63) * 2;
    const int g = node0 + m;
    unsigned int pack = 0;
    if (g < n_nodes) {
      if (isf) {
        const float* hp = (const float*)h + (size_t)g * HD + kk;
        const float f0 = hp[0], f1 = hp[1];
        const __hip_bfloat16 b0 = __float2bfloat16(f0);
        const __hip_bfloat16 b1 = __float2bfloat16(f1);
        pack = (unsigned int)(*(const unsigned short*)&b0) |
               ((unsigned int)(*(const unsigned short*)&b1) << 16);
      } else {
        pack = *(const unsigned int*)((const __hip_bfloat16*)h +
                                      (size_t)g * HD + kk);
      }
    }
    *(unsigned int*)&As[m * KP + kk] = pack;
  }
  __syncthreads();

  const int wave = tid >> 6;
  const int lane = tid & 63;
  const int l15 = lane & 15;
  const int quad = lane >> 4;

  s16x8 afrag[4];
#pragma unroll
  for (int k4 = 0; k4 < 4; ++k4)
    afrag[k4] = *(const s16x8*)&As[(wave * 16 + l15) * KP + k4 * 32 + quad * 8];

  for (int c = 0; c < 3; ++c) {
    __syncthreads();
    const uint4* gsrc = (const uint4*)(Wt + (size_t)c * NCH * KP);
    for (int j = tid; j < (NCH * KP * 2) / 16; j += 256)
      ((uint4*)Bs)[j] = gsrc[j];
    __syncthreads();

    f32x4 acc[8];
#pragma unroll
    for (int t = 0; t < 8; ++t) acc[t] = (f32x4){0.f, 0.f, 0.f, 0.f};

#pragma unroll
    for (int t = 0; t < 8; ++t) {
#pragma unroll
      for (int k4 = 0; k4 < 4; ++k4) {
        const s16x8 bfrag =
            *(const s16x8*)&Bs[(t * 16 + l15) * KP + k4 * 32 + quad * 8];
        acc[t] = __builtin_amdgcn_mfma_f32_16x16x32_bf16(afrag[k4], bfrag,
                                                         acc[t], 0, 0, 0);
      }
    }

    const void* bp = (c == 0) ? bq : (c == 1) ? bk : bv;
#pragma unroll
    for (int t = 0; t < 8; ++t) {
      const int ncol = t * 16 + l15;
      const float bias = isf ? ((const float*)bp)[ncol]
                             : __bfloat162float(((const __hip_bfloat16*)bp)[ncol]);
#pragma unroll
      for (int r = 0; r < 4; ++r) {
        const int g = node0 + wave * 16 + quad * 4 + r;
        if (g < n_nodes) {
          const float val = acc[t][r] + bias;
          const size_t o = (size_t)g * HD + ncol;
          if (c == 0)      Qf[o] = val;
          else if (c == 1) Kb[o] = __float2bfloat16(val);
          else             Vb[o] = __float2bfloat16(val);
        }
      }
    }
  }
}

// ---------------------------------------------------------------------------
// CSR build, packed two-level path (n_nodes <= 65536).
// Bucket = dst >> 8 (256 nodes/bucket).  Edge packed as (src<<16)|dst.
// ---------------------------------------------------------------------------
__global__ __launch_bounds__(256) void bucket_hist_kernel(
    const int* __restrict__ dst, int* __restrict__ bucket_size, int n_edges) {
  __shared__ int lh[256];
  const int t = threadIdx.x;
  const int e0 = blockIdx.x * CHUNK;
  const int e1 = (e0 + CHUNK < n_edges) ? e0 + CHUNK : n_edges;
  lh[t] = 0;
  __syncthreads();
  for (int e = e0 + t; e < e1; e += 256) atomicAdd(&lh[dst[e] >> 8], 1);
  __syncthreads();
  if (lh[t] > 0) atomicAdd(&bucket_size[t], lh[t]);
}

__global__ __launch_bounds__(256) void bucket_scan_kernel(
    const int* __restrict__ bucket_size, int* __restrict__ bucket_base,
    int* __restrict__ bucket_cur, int nbuck, int n_edges) {
  __shared__ int sh[256];
  const int t = threadIdx.x;
  const int v = (t < nbuck) ? bucket_size[t] : 0;
  sh[t] = v;
  __syncthreads();
  for (int off = 1; off < 256; off <<= 1) {
    int add = (t >= off) ? sh[t - off] : 0;
    __syncthreads();
    sh[t] += add;
    __syncthreads();
  }
  const int excl = sh[t] - v;
  if (t < nbuck) {
    bucket_base[t] = excl;
    bucket_cur[t] = excl;
  }
  if (t == 0) bucket_base[nbuck] = n_edges;
}

// Pass A: block-aggregated bucket scatter; writes land in ~contiguous runs.
__global__ __launch_bounds__(256) void bucketize_kernel(
    const int* __restrict__ src, const int* __restrict__ dst,
    int* __restrict__ bucket_cur, unsigned int* __restrict__ ebuf,
    int n_edges) {
  __shared__ int lh[256];
  const int t = threadIdx.x;
  const int e0 = blockIdx.x * CHUNK;
  const int e1 = (e0 + CHUNK < n_edges) ? e0 + CHUNK : n_edges;
  lh[t] = 0;
  __syncthreads();
  for (int e = e0 + t; e < e1; e += 256) atomicAdd(&lh[dst[e] >> 8], 1);
  __syncthreads();
  const int cnt_local = lh[t];
  int base = 0;
  if (cnt_local > 0) base = atomicAdd(&bucket_cur[t], cnt_local);
  __syncthreads();
  lh[t] = base;  // reuse as block-local cursor
  __syncthreads();
  for (int e = e0 + t; e < e1; e += 256) {
    const int d = dst[e];
    const int pos = atomicAdd(&lh[d >> 8], 1);
    ebuf[pos] = ((unsigned int)src[e] << 16) | (unsigned int)d;
  }
}

// Pass B1: per-dst counts.  One block owns one bucket -> LDS counters only.
__global__ __launch_bounds__(256) void bcount_kernel(
    const unsigned int* __restrict__ ebuf, const int* __restrict__ bucket_base,
    int* __restrict__ cnt, int n_nodes) {
  __shared__ int lc[256];
  const int b = blockIdx.x;
  const int t = threadIdx.x;
  const int lo = bucket_base[b], hi = bucket_base[b + 1];
  const int nbase = b << 8;
  lc[t] = 0;
  __syncthreads();
  for (int i = lo + t; i < hi; i += 256)
    atomicAdd(&lc[(ebuf[i] & 0xFFFFu) - nbase], 1);
  __syncthreads();
  const int node = nbase + t;
  if (node < n_nodes) cnt[node] = lc[t];
}

// Pass B2: final scatter.  LDS cursors init from row_ptr; writes hit a
// ~32KB L2-resident window -> lines filled, no write amplification.
__global__ __launch_bounds__(256) void bscatter_kernel(
    const unsigned int* __restrict__ ebuf, const int* __restrict__ bucket_base,
    const int* __restrict__ row_ptr, int* __restrict__ edge_src, int n_nodes) {
  __shared__ int lcur[256];
  const int b = blockIdx.x;
  const int t = threadIdx.x;
  const int lo = bucket_base[b], hi = bucket_base[b + 1];
  const int nbase = b << 8;
  const int node = nbase + t;
  lcur[t] = (node < n_nodes) ? row_ptr[node] : 0;
  __syncthreads();
  for (int i = lo + t; i < hi; i += 256) {
    const unsigned int p = ebuf[i];
    const int pos = atomicAdd(&lcur[(p & 0xFFFFu) - nbase], 1);
    edge_src[pos] = (int)(p >> 16);
  }
}

// ---------------------------------------------------------------------------
// Fallback CSR build (n_nodes > 65536): direct hist + scatter.
// ---------------------------------------------------------------------------
__global__ __launch_bounds__(256) void hist_kernel(
    const int* __restrict__ dst, int* __restrict__ cnt, int n_edges) {
  const int e = blockIdx.x * blockDim.x + threadIdx.x;
  if (e < n_edges) atomicAdd(&cnt[dst[e]], 1);
}

__global__ __launch_bounds__(256) void scatter_kernel(
    const int* __restrict__ src, const int* __restrict__ dst,
    int* __restrict__ cursor, int* __restrict__ edge_src, int n_edges) {
  const int e = blockIdx.x * blockDim.x + threadIdx.x;
  if (e < n_edges) {
    const int pos = atomicAdd(&cursor[dst[e]], 1);
    edge_src[pos] = src[e];
  }
}

// ---------------------------------------------------------------------------
// Row-pointer scan (over cnt).
// ---------------------------------------------------------------------------
__global__ __launch_bounds__(SCAN_B) void scan1_kernel(
    const int* __restrict__ cnt, int* __restrict__ exs,
    int* __restrict__ bsum, int n) {
  __shared__ int sh[SCAN_B];
  const int t = threadIdx.x;
  const int i = blockIdx.x * SCAN_B + t;
  int v = (i < n) ? cnt[i] : 0;
  sh[t] = v;
  __syncthreads();
  for (int off = 1; off < SCAN_B; off <<= 1) {
    int add = (t >= off) ? sh[t - off] : 0;
    __syncthreads();
    sh[t] += add;
    __syncthreads();
  }
  if (i < n) exs[i] = sh[t] - v;
  if (t == SCAN_B - 1) bsum[blockIdx.x] = sh[t];
}

__global__ __launch_bounds__(SCAN_B) void scan2_kernel(int* __restrict__ bsum,
                                                       int nb) {
  __shared__ int sh[SCAN_B];
  const int t = threadIdx.x;
  if (nb <= SCAN_B) {
    int v = (t < nb) ? bsum[t] : 0;
    sh[t] = v;
    __syncthreads();
    for (int off = 1; off < SCAN_B; off <<= 1) {
      int add = (t >= off) ? sh[t - off] : 0;
      __syncthreads();
      sh[t] += add;
      __syncthreads();
    }
    if (t < nb) bsum[t] = sh[t] - v;
  } else if (t == 0) {
    int run = 0;
    for (int b = 0; b < nb; ++b) { int v = bsum[b]; bsum[b] = run; run += v; }
  }
}

__global__ __launch_bounds__(SCAN_B) void scan3_kernel(
    const int* __restrict__ exs, const int* __restrict__ bsum,
    int* __restrict__ row_ptr, int* __restrict__ cursor, int n, int n_edges) {
  const int i = blockIdx.x * SCAN_B + threadIdx.x;
  if (i < n) {
    const int v = exs[i] + bsum[blockIdx.x];
    row_ptr[i] = v;
    cursor[i] = v;
  }
  if (i == 0) row_ptr[n] = n_edges;
}

// ---------------------------------------------------------------------------
// Kernel 3: per-destination gather, two-phase per 16-edge group.
// ---------------------------------------------------------------------------
__global__ __launch_bounds__(128) void gather_kernel(
    const int* __restrict__ row_ptr, const int* __restrict__ edge_src,
    const float* __restrict__ Qf, const __hip_bfloat16* __restrict__ Kb,
    const __hip_bfloat16* __restrict__ Vb,
    void* __restrict__ out, const int* __restrict__ flag, int n_nodes) {
  __shared__ float sc[2][16 * HH];
  __shared__ int   ss[2][16];

  const int d = blockIdx.x;
  const int tid = threadIdx.x;

  const int eloc = tid >> 3;
  const int hh8  = tid & 7;
  const int hd16 = tid >> 4;

  const int start = row_ptr[d];
  const int deg = row_ptr[d + 1] - start;

  float qreg[16];
  {
    const f32x4* qp = (const f32x4*)(Qf + (size_t)d * HD + hh8 * 16);
#pragma unroll
    for (int j = 0; j < 4; ++j) {
      const f32x4 q4 = qp[j];
      qreg[j * 4 + 0] = q4[0] * 0.25f;
      qreg[j * 4 + 1] = q4[1] * 0.25f;
      qreg[j * 4 + 2] = q4[2] * 0.25f;
      qreg[j * 4 + 3] = q4[3] * 0.25f;
    }
  }

  float accV = 0.0f, accZ = 0.0f;
  const int ngroups = (deg + 15) >> 4;

  for (int g = 0; g < ngroups; ++g) {
    const int buf = g & 1;
    const int ei = g * 16 + eloc;

    float score = 0.0f;
    int s = 0;
    if (ei < deg) {
      s = edge_src[start + ei];
      const uint4* kp = (const uint4*)(Kb + (size_t)s * HD + hh8 * 16);
      unsigned int kw[8];
      *(uint4*)&kw[0] = kp[0];
      *(uint4*)&kw[4] = kp[1];
      float dot = 0.0f;
#pragma unroll
      for (int i = 0; i < 8; ++i) {
        const float klo = __uint_as_float(kw[i] << 16);
        const float khi = __uint_as_float(kw[i] & 0xFFFF0000u);
        dot = fmaf(qreg[2 * i], klo, dot);
        dot = fmaf(qreg[2 * i + 1], khi, dot);
      }
      score = __expf(fminf(fmaxf(dot, -5.0f), 5.0f));
    }
    sc[buf][eloc * HH + hh8] = score;
    if (hh8 == 0) ss[buf][eloc] = s;
    __syncthreads();

    const int lim = (deg - g * 16 < 16) ? (deg - g * 16) : 16;
    if (lim == 16) {
#pragma unroll
      for (int e = 0; e < 16; ++e) {
        const int s2 = ss[buf][e];
        const float sco = sc[buf][e * HH + hd16];
        const unsigned short vu = *(const unsigned short*)(Vb + (size_t)s2 * HD + tid);
        const float v = __uint_as_float(((unsigned int)vu) << 16);
        accV = fmaf(sco, v, accV);
        accZ += sco;
      }
    } else {
      for (int e = 0; e < lim; ++e) {
        const int s2 = ss[buf][e];
        const float sco = sc[buf][e * HH + hd16];
        const unsigned short vu = *(const unsigned short*)(Vb + (size_t)s2 * HD + tid);
        const float v = __uint_as_float(((unsigned int)vu) << 16);
        accV = fmaf(sco, v, accV);
        accZ += sco;
      }
    }
  }

  const float r = accV / (accZ + 1e-6f);
  const size_t o = (size_t)d * HD + tid;
  if (*flag) ((float*)out)[o] = r;
  else       ((__hip_bfloat16*)out)[o] = __float2bfloat16(r);
}

// ---------------------------------------------------------------------------
extern "C" void kernel_launch(void* const* d_in, const int* in_sizes, int n_in,
                              void* d_out, int out_size, void* d_ws, size_t ws_size,
                              hipStream_t stream) {
  const void* h  = d_in[0];
  const void* Wq = d_in[1];
  const void* bq = d_in[2];
  const void* Wk = d_in[3];
  const void* bk = d_in[4];
  const void* Wv = d_in[5];
  const void* bv = d_in[6];
  const int* src = (const int*)d_in[7];
  const int* dst = (const int*)d_in[8];

  const int n_nodes = in_sizes[0] / IN_DIM;  // 50000
  const int n_edges = in_sizes[7];           // 1600000
  const int nb = (n_nodes + SCAN_B - 1) / SCAN_B;
  const int nbuck = (n_nodes + 255) >> 8;

  // workspace layout (256B-aligned chunks)
  char* p = (char*)d_ws;
  int* flag = (int*)p;                       p += 256;
  float* Qf = (float*)p;                     p += (size_t)n_nodes * HD * 4;
  __hip_bfloat16* Kb = (__hip_bfloat16*)p;   p += (size_t)n_nodes * HD * 2;
  __hip_bfloat16* Vb = (__hip_bfloat16*)p;   p += (size_t)n_nodes * HD * 2;
  __hip_bfloat16* Wt = (__hip_bfloat16*)p;   p += ((size_t)384 * KP * 2 + 255) / 256 * 256;
  int* cnt = (int*)p;                        p += (size_t)n_nodes * 4;
  int* bucket_size = (int*)p;                p += 258 * 4;   // memset with cnt
  int* bucket_base = (int*)p;                p += 258 * 4;
  int* bucket_cur = (int*)p;                 p += 258 * 4;
  int* exs = (int*)p;                        p += (size_t)n_nodes * 4;
  int* bsum = (int*)p;                       p += (size_t)(nb + 1) * 4;
  int* row_ptr = (int*)p;                    p += (size_t)(n_nodes + 1) * 4;
  int* cursor = (int*)p;                     p += (size_t)n_nodes * 4;
  unsigned int* ebuf = (unsigned int*)p;     p += (size_t)n_edges * 4;
  int* edge_src = (int*)p;                   p += (size_t)n_edges * 4;

  sniff_kernel<<<1, 64, 0, stream>>>((const unsigned short*)h, flag);
  // zero cnt + bucket_size in one shot (adjacent)
  hipMemsetAsync(cnt, 0, ((size_t)n_nodes + 258) * sizeof(int), stream);

  wt_kernel<<<384, 128, 0, stream>>>(Wq, Wk, Wv, Wt, flag);

  const int pgrid = (n_nodes + MT - 1) / MT;
  proj_kernel<<<pgrid, 256, 0, stream>>>(h, Wt, bq, bk, bv, Qf, Kb, Vb, flag,
                                         n_nodes);

  const int nchunk = (n_edges + CHUNK - 1) / CHUNK;
  if (n_nodes <= 65536) {
    // packed two-level CSR build
    bucket_hist_kernel<<<nchunk, 256, 0, stream>>>(dst, bucket_size, n_edges);
    bucket_scan_kernel<<<1, 256, 0, stream>>>(bucket_size, bucket_base,
                                              bucket_cur, nbuck, n_edges);
    bucketize_kernel<<<nchunk, 256, 0, stream>>>(src, dst, bucket_cur, ebuf,
                                                 n_edges);
    bcount_kernel<<<nbuck, 256, 0, stream>>>(ebuf, bucket_base, cnt, n_nodes);
    scan1_kernel<<<nb, SCAN_B, 0, stream>>>(cnt, exs, bsum, n_nodes);
    scan2_kernel<<<1, SCAN_B, 0, stream>>>(bsum, nb);
    scan3_kernel<<<nb, SCAN_B, 0, stream>>>(exs, bsum, row_ptr, cursor,
                                            n_nodes, n_edges);
    bscatter_kernel<<<nbuck, 256, 0, stream>>>(ebuf, bucket_base, row_ptr,
                                               edge_src, n_nodes);
  } else {
    // fallback: direct hist + scatter
    const int eb = 256;
    const int egrid = (n_edges + eb - 1) / eb;
    hist_kernel<<<egrid, eb, 0, stream>>>(dst, cnt, n_edges);
    scan1_kernel<<<nb, SCAN_B, 0, stream>>>(cnt, exs, bsum, n_nodes);
    scan2_kernel<<<1, SCAN_B, 0, stream>>>(bsum, nb);
    scan3_kernel<<<nb, SCAN_B, 0, stream>>>(exs, bsum, row_ptr, cursor,
                                            n_nodes, n_edges);
    scatter_kernel<<<egrid, eb, 0, stream>>>(src, dst, cursor, edge_src,
                                             n_edges);
  }

  gather_kernel<<<n_nodes, 128, 0, stream>>>(row_ptr, edge_src, Qf, Kb, Vb,
                                             d_out, flag, n_nodes);
}

// Round 7
// 339.778 us; speedup vs baseline: 3.6371x; 1.0062x over previous
//
#include <hip/hip_runtime.h>
#include <hip/hip_bf16.h>

#define IN_DIM 128
#define HH 8
#define DD 16
#define HD 128   // H*D
#define SCAN_B 256
#define CHUNK 8192  // edges per bucketize block

#define MT  64   // nodes per proj block
#define KP  136  // padded K stride for Wt (bf16 elems)
#define NCH 128  // output-channel chunk staged in LDS

typedef float f32x4 __attribute__((ext_vector_type(4)));
typedef short s16x8 __attribute__((ext_vector_type(8)));

// ---------------------------------------------------------------------------
// Kernel 0: dtype sniff.  flag = 1 -> fp32 storage, 0 -> bf16 storage.
// ---------------------------------------------------------------------------
__global__ void sniff_kernel(const unsigned short* __restrict__ h_raw,
                             int* __restrict__ flag) {
  if (threadIdx.x == 0 && blockIdx.x == 0) {
    int sane = 0;
    for (int i = 0; i < 128; i += 2) {
      const unsigned short u = h_raw[i];
      const int expo = (u >> 7) & 0xFF;
      if (expo >= 112 && expo <= 143) sane++;
    }
    *flag = (sane >= 40) ? 0 : 1;
  }
}

// ---------------------------------------------------------------------------
// Kernel 1: W^T staging.  Wt[n][k] bf16, n in [0,384), padded stride KP.
// ---------------------------------------------------------------------------
__global__ __launch_bounds__(128) void wt_kernel(
    const void* __restrict__ Wq, const void* __restrict__ Wk,
    const void* __restrict__ Wv, __hip_bfloat16* __restrict__ Wt,
    const int* __restrict__ flag) {
  const int n = blockIdx.x;
  const int k = threadIdx.x;
  const int mat = n >> 7;
  const int col = n & 127;
  const void* W = (mat == 0) ? Wq : (mat == 1) ? Wk : Wv;
  float v;
  if (*flag) v = ((const float*)W)[(size_t)k * HD + col];
  else       v = __bfloat162float(((const __hip_bfloat16*)W)[(size_t)k * HD + col]);
  Wt[(size_t)n * KP + k] = __float2bfloat16(v);
}

// ---------------------------------------------------------------------------
// Kernel 2: MFMA projection.  [N x 128] @ [128 x 384] + bias.
// ---------------------------------------------------------------------------
__global__ __launch_bounds__(256) void proj_kernel(
    const void* __restrict__ h, const __hip_bfloat16* __restrict__ Wt,
    const void* __restrict__ bq, const void* __restrict__ bk,
    const void* __restrict__ bv,
    float* __restrict__ Qf, __hip_bfloat16* __restrict__ Kb,
    __hip_bfloat16* __restrict__ Vb,
    const int* __restrict__ flag, int n_nodes) {
  __shared__ short Bs[NCH * KP];
  __shared__ short As[MT * KP];

  const int tid = threadIdx.x;
  const int node0 = blockIdx.x * MT;
  const int isf = *flag;

#pragma unroll
  for (int j = 0; j < 16; ++j) {
    const int pid = tid + j * 256;
    const int m = pid >> 6;
    const int kk = (pid & 63) * 2;
    const int g = node0 + m;
    unsigned int pack = 0;
    if (g < n_nodes) {
      if (isf) {
        const float* hp = (const float*)h + (size_t)g * HD + kk;
        const float f0 = hp[0], f1 = hp[1];
        const __hip_bfloat16 b0 = __float2bfloat16(f0);
        const __hip_bfloat16 b1 = __float2bfloat16(f1);
        pack = (unsigned int)(*(const unsigned short*)&b0) |
               ((unsigned int)(*(const unsigned short*)&b1) << 16);
      } else {
        pack = *(const unsigned int*)((const __hip_bfloat16*)h +
                                      (size_t)g * HD + kk);
      }
    }
    *(unsigned int*)&As[m * KP + kk] = pack;
  }
  __syncthreads();

  const int wave = tid >> 6;
  const int lane = tid & 63;
  const int l15 = lane & 15;
  const int quad = lane >> 4;

  s16x8 afrag[4];
#pragma unroll
  for (int k4 = 0; k4 < 4; ++k4)
    afrag[k4] = *(const s16x8*)&As[(wave * 16 + l15) * KP + k4 * 32 + quad * 8];

  for (int c = 0; c < 3; ++c) {
    __syncthreads();
    const uint4* gsrc = (const uint4*)(Wt + (size_t)c * NCH * KP);
    for (int j = tid; j < (NCH * KP * 2) / 16; j += 256)
      ((uint4*)Bs)[j] = gsrc[j];
    __syncthreads();

    f32x4 acc[8];
#pragma unroll
    for (int t = 0; t < 8; ++t) acc[t] = (f32x4){0.f, 0.f, 0.f, 0.f};

#pragma unroll
    for (int t = 0; t < 8; ++t) {
#pragma unroll
      for (int k4 = 0; k4 < 4; ++k4) {
        const s16x8 bfrag =
            *(const s16x8*)&Bs[(t * 16 + l15) * KP + k4 * 32 + quad * 8];
        acc[t] = __builtin_amdgcn_mfma_f32_16x16x32_bf16(afrag[k4], bfrag,
                                                         acc[t], 0, 0, 0);
      }
    }

    const void* bp = (c == 0) ? bq : (c == 1) ? bk : bv;
#pragma unroll
    for (int t = 0; t < 8; ++t) {
      const int ncol = t * 16 + l15;
      const float bias = isf ? ((const float*)bp)[ncol]
                             : __bfloat162float(((const __hip_bfloat16*)bp)[ncol]);
#pragma unroll
      for (int r = 0; r < 4; ++r) {
        const int g = node0 + wave * 16 + quad * 4 + r;
        if (g < n_nodes) {
          const float val = acc[t][r] + bias;
          const size_t o = (size_t)g * HD + ncol;
          if (c == 0)      Qf[o] = val;
          else if (c == 1) Kb[o] = __float2bfloat16(val);
          else             Vb[o] = __float2bfloat16(val);
        }
      }
    }
  }
}

// ---------------------------------------------------------------------------
// CSR build, packed two-level path (n_nodes <= 65536).
// Bucket = dst >> 8 (256 nodes/bucket).  Edge packed as (src<<16)|dst.
// ---------------------------------------------------------------------------
__global__ __launch_bounds__(256) void bucket_hist_kernel(
    const int* __restrict__ dst, int* __restrict__ bucket_size, int n_edges) {
  __shared__ int lh[256];
  const int t = threadIdx.x;
  const int e0 = blockIdx.x * CHUNK;
  const int e1 = (e0 + CHUNK < n_edges) ? e0 + CHUNK : n_edges;
  lh[t] = 0;
  __syncthreads();
  for (int e = e0 + t; e < e1; e += 256) atomicAdd(&lh[dst[e] >> 8], 1);
  __syncthreads();
  if (lh[t] > 0) atomicAdd(&bucket_size[t], lh[t]);
}

__global__ __launch_bounds__(256) void bucket_scan_kernel(
    const int* __restrict__ bucket_size, int* __restrict__ bucket_base,
    int* __restrict__ bucket_cur, int nbuck, int n_edges) {
  __shared__ int sh[256];
  const int t = threadIdx.x;
  const int v = (t < nbuck) ? bucket_size[t] : 0;
  sh[t] = v;
  __syncthreads();
  for (int off = 1; off < 256; off <<= 1) {
    int add = (t >= off) ? sh[t - off] : 0;
    __syncthreads();
    sh[t] += add;
    __syncthreads();
  }
  const int excl = sh[t] - v;
  if (t < nbuck) {
    bucket_base[t] = excl;
    bucket_cur[t] = excl;
  }
  if (t == 0) bucket_base[nbuck] = n_edges;
}

// Pass A: block-aggregated bucket scatter; writes land in ~contiguous runs.
__global__ __launch_bounds__(256) void bucketize_kernel(
    const int* __restrict__ src, const int* __restrict__ dst,
    int* __restrict__ bucket_cur, unsigned int* __restrict__ ebuf,
    int n_edges) {
  __shared__ int lh[256];
  const int t = threadIdx.x;
  const int e0 = blockIdx.x * CHUNK;
  const int e1 = (e0 + CHUNK < n_edges) ? e0 + CHUNK : n_edges;
  lh[t] = 0;
  __syncthreads();
  for (int e = e0 + t; e < e1; e += 256) atomicAdd(&lh[dst[e] >> 8], 1);
  __syncthreads();
  const int cnt_local = lh[t];
  int base = 0;
  if (cnt_local > 0) base = atomicAdd(&bucket_cur[t], cnt_local);
  __syncthreads();
  lh[t] = base;
  __syncthreads();
  for (int e = e0 + t; e < e1; e += 256) {
    const int d = dst[e];
    const int pos = atomicAdd(&lh[d >> 8], 1);
    ebuf[pos] = ((unsigned int)src[e] << 16) | (unsigned int)d;
  }
}

// Fused pass B: per-bucket count -> LDS scan -> row_ptr -> LDS-cursor scatter.
// One block owns one bucket exclusively; zero global atomics.
__global__ __launch_bounds__(256) void bucket_csr_kernel(
    const unsigned int* __restrict__ ebuf, const int* __restrict__ bucket_base,
    int* __restrict__ row_ptr, int* __restrict__ edge_src,
    int n_nodes, int nbuck) {
  __shared__ int lc[256];
  __shared__ int sh[256];
  const int b = blockIdx.x;
  const int t = threadIdx.x;
  const int lo = bucket_base[b], hi = bucket_base[b + 1];
  const int nbase = b << 8;

  lc[t] = 0;
  __syncthreads();
  for (int i = lo + t; i < hi; i += 256)
    atomicAdd(&lc[(ebuf[i] & 0xFFFFu) - nbase], 1);
  __syncthreads();

  const int v = lc[t];
  sh[t] = v;
  __syncthreads();
  for (int off = 1; off < 256; off <<= 1) {
    int add = (t >= off) ? sh[t - off] : 0;
    __syncthreads();
    sh[t] += add;
    __syncthreads();
  }
  const int excl = sh[t] - v;  // exclusive within bucket

  const int node = nbase + t;
  if (node < n_nodes) row_ptr[node] = lo + excl;
  if (b == nbuck - 1 && t == 255) row_ptr[n_nodes] = hi;

  __syncthreads();
  lc[t] = lo + excl;  // cursor
  __syncthreads();
  for (int i = lo + t; i < hi; i += 256) {
    const unsigned int pkd = ebuf[i];
    const int pos = atomicAdd(&lc[(pkd & 0xFFFFu) - nbase], 1);
    edge_src[pos] = (int)(pkd >> 16);
  }
}

// ---------------------------------------------------------------------------
// Fallback CSR build (n_nodes > 65536): direct hist + scans + scatter.
// ---------------------------------------------------------------------------
__global__ __launch_bounds__(256) void hist_kernel(
    const int* __restrict__ dst, int* __restrict__ cnt, int n_edges) {
  const int e = blockIdx.x * blockDim.x + threadIdx.x;
  if (e < n_edges) atomicAdd(&cnt[dst[e]], 1);
}

__global__ __launch_bounds__(256) void scatter_kernel(
    const int* __restrict__ src, const int* __restrict__ dst,
    int* __restrict__ cursor, int* __restrict__ edge_src, int n_edges) {
  const int e = blockIdx.x * blockDim.x + threadIdx.x;
  if (e < n_edges) {
    const int pos = atomicAdd(&cursor[dst[e]], 1);
    edge_src[pos] = src[e];
  }
}

__global__ __launch_bounds__(SCAN_B) void scan1_kernel(
    const int* __restrict__ cnt, int* __restrict__ exs,
    int* __restrict__ bsum, int n) {
  __shared__ int sh[SCAN_B];
  const int t = threadIdx.x;
  const int i = blockIdx.x * SCAN_B + t;
  int v = (i < n) ? cnt[i] : 0;
  sh[t] = v;
  __syncthreads();
  for (int off = 1; off < SCAN_B; off <<= 1) {
    int add = (t >= off) ? sh[t - off] : 0;
    __syncthreads();
    sh[t] += add;
    __syncthreads();
  }
  if (i < n) exs[i] = sh[t] - v;
  if (t == SCAN_B - 1) bsum[blockIdx.x] = sh[t];
}

__global__ __launch_bounds__(SCAN_B) void scan2_kernel(int* __restrict__ bsum,
                                                       int nb) {
  __shared__ int sh[SCAN_B];
  const int t = threadIdx.x;
  if (nb <= SCAN_B) {
    int v = (t < nb) ? bsum[t] : 0;
    sh[t] = v;
    __syncthreads();
    for (int off = 1; off < SCAN_B; off <<= 1) {
      int add = (t >= off) ? sh[t - off] : 0;
      __syncthreads();
      sh[t] += add;
      __syncthreads();
    }
    if (t < nb) bsum[t] = sh[t] - v;
  } else if (t == 0) {
    int run = 0;
    for (int b = 0; b < nb; ++b) { int v = bsum[b]; bsum[b] = run; run += v; }
  }
}

__global__ __launch_bounds__(SCAN_B) void scan3_kernel(
    const int* __restrict__ exs, const int* __restrict__ bsum,
    int* __restrict__ row_ptr, int* __restrict__ cursor, int n, int n_edges) {
  const int i = blockIdx.x * SCAN_B + threadIdx.x;
  if (i < n) {
    const int v = exs[i] + bsum[blockIdx.x];
    row_ptr[i] = v;
    cursor[i] = v;
  }
  if (i == 0) row_ptr[n] = n_edges;
}

// ---------------------------------------------------------------------------
// Kernel 3: per-destination gather, two-phase per 16-edge group.
//   Score stage: thread = (edge 0..15, head 0..7); K row 2x16B loads, one
//     exp per (edge,head), no shuffles.
//   V stage: thread = (channel-pair 0..63, edge-parity 0..1); one uint load
//     = 2 bf16 V channels per edge, 8 edges per thread; partner thread
//     (tid^64) covers the other 8.  LDS combine once at block end.
// ---------------------------------------------------------------------------
__global__ __launch_bounds__(128) void gather_kernel(
    const int* __restrict__ row_ptr, const int* __restrict__ edge_src,
    const float* __restrict__ Qf, const __hip_bfloat16* __restrict__ Kb,
    const __hip_bfloat16* __restrict__ Vb,
    void* __restrict__ out, const int* __restrict__ flag, int n_nodes) {
  __shared__ float sc[2][16 * HH];
  __shared__ int   ss[2][16];
  __shared__ float comb[64 * 3];

  const int d = blockIdx.x;
  const int tid = threadIdx.x;

  // score-stage role
  const int eloc = tid >> 3;
  const int hh8  = tid & 7;
  // V-stage role
  const int pr    = tid & 63;  // channel pair -> channels 2pr, 2pr+1
  const int half  = tid >> 6;  // edge parity
  const int headp = pr >> 3;   // head of this channel pair

  const int start = row_ptr[d];
  const int deg = row_ptr[d + 1] - start;

  float qreg[16];
  {
    const f32x4* qp = (const f32x4*)(Qf + (size_t)d * HD + hh8 * 16);
#pragma unroll
    for (int j = 0; j < 4; ++j) {
      const f32x4 q4 = qp[j];
      qreg[j * 4 + 0] = q4[0] * 0.25f;
      qreg[j * 4 + 1] = q4[1] * 0.25f;
      qreg[j * 4 + 2] = q4[2] * 0.25f;
      qreg[j * 4 + 3] = q4[3] * 0.25f;
    }
  }

  float aV0 = 0.0f, aV1 = 0.0f, aZ = 0.0f;
  const int ngroups = (deg + 15) >> 4;

  for (int g = 0; g < ngroups; ++g) {
    const int buf = g & 1;
    const int ei = g * 16 + eloc;

    float score = 0.0f;
    int s = 0;
    if (ei < deg) {
      s = edge_src[start + ei];
      const uint4* kp = (const uint4*)(Kb + (size_t)s * HD + hh8 * 16);
      unsigned int kw[8];
      *(uint4*)&kw[0] = kp[0];
      *(uint4*)&kw[4] = kp[1];
      float dot = 0.0f;
#pragma unroll
      for (int i = 0; i < 8; ++i) {
        const float klo = __uint_as_float(kw[i] << 16);
        const float khi = __uint_as_float(kw[i] & 0xFFFF0000u);
        dot = fmaf(qreg[2 * i], klo, dot);
        dot = fmaf(qreg[2 * i + 1], khi, dot);
      }
      score = __expf(fminf(fmaxf(dot, -5.0f), 5.0f));
    }
    sc[buf][eloc * HH + hh8] = score;
    if (hh8 == 0) ss[buf][eloc] = s;
    __syncthreads();

    const int rem = deg - g * 16;
    const int lim = (rem < 16) ? rem : 16;
    if (lim == 16) {
#pragma unroll
      for (int j = 0; j < 8; ++j) {
        const int e = 2 * j + half;
        const int s2 = ss[buf][e];
        const float sco = sc[buf][e * HH + headp];
        const unsigned int vv =
            *(const unsigned int*)(Vb + (size_t)s2 * HD + 2 * pr);
        aV0 = fmaf(sco, __uint_as_float(vv << 16), aV0);
        aV1 = fmaf(sco, __uint_as_float(vv & 0xFFFF0000u), aV1);
        aZ += sco;
      }
    } else {
      for (int e = half; e < lim; e += 2) {
        const int s2 = ss[buf][e];
        const float sco = sc[buf][e * HH + headp];
        const unsigned int vv =
            *(const unsigned int*)(Vb + (size_t)s2 * HD + 2 * pr);
        aV0 = fmaf(sco, __uint_as_float(vv << 16), aV0);
        aV1 = fmaf(sco, __uint_as_float(vv & 0xFFFF0000u), aV1);
        aZ += sco;
      }
    }
  }

  // combine the two edge-parity halves
  if (half == 1) {
    comb[pr] = aV0;
    comb[64 + pr] = aV1;
    comb[128 + pr] = aZ;
  }
  __syncthreads();
  if (half == 0) {
    aV0 += comb[pr];
    aV1 += comb[64 + pr];
    aZ  += comb[128 + pr];
    const float inv = 1.0f / (aZ + 1e-6f);
    const float r0 = aV0 * inv;
    const float r1 = aV1 * inv;
    if (*flag) {
      float2* op = (float2*)((float*)out + (size_t)d * HD + 2 * pr);
      *op = make_float2(r0, r1);
    } else {
      const __hip_bfloat16 b0 = __float2bfloat16(r0);
      const __hip_bfloat16 b1 = __float2bfloat16(r1);
      const unsigned int pk = (unsigned int)(*(const unsigned short*)&b0) |
                              ((unsigned int)(*(const unsigned short*)&b1) << 16);
      *(unsigned int*)((__hip_bfloat16*)out + (size_t)d * HD + 2 * pr) = pk;
    }
  }
}

// ---------------------------------------------------------------------------
extern "C" void kernel_launch(void* const* d_in, const int* in_sizes, int n_in,
                              void* d_out, int out_size, void* d_ws, size_t ws_size,
                              hipStream_t stream) {
  const void* h  = d_in[0];
  const void* Wq = d_in[1];
  const void* bq = d_in[2];
  const void* Wk = d_in[3];
  const void* bk = d_in[4];
  const void* Wv = d_in[5];
  const void* bv = d_in[6];
  const int* src = (const int*)d_in[7];
  const int* dst = (const int*)d_in[8];

  const int n_nodes = in_sizes[0] / IN_DIM;  // 50000
  const int n_edges = in_sizes[7];           // 1600000
  const int nb = (n_nodes + SCAN_B - 1) / SCAN_B;
  const int nbuck = (n_nodes + 255) >> 8;

  // workspace layout (256B-aligned chunks)
  char* p = (char*)d_ws;
  int* flag = (int*)p;                       p += 256;
  float* Qf = (float*)p;                     p += (size_t)n_nodes * HD * 4;
  __hip_bfloat16* Kb = (__hip_bfloat16*)p;   p += (size_t)n_nodes * HD * 2;
  __hip_bfloat16* Vb = (__hip_bfloat16*)p;   p += (size_t)n_nodes * HD * 2;
  __hip_bfloat16* Wt = (__hip_bfloat16*)p;   p += ((size_t)384 * KP * 2 + 255) / 256 * 256;
  int* bucket_size = (int*)p;                p += 258 * 4;
  int* bucket_base = (int*)p;                p += 258 * 4;
  int* bucket_cur = (int*)p;                 p += 258 * 4;
  int* row_ptr = (int*)p;                    p += (size_t)(n_nodes + 1) * 4;
  unsigned int* ebuf = (unsigned int*)p;     p += (size_t)n_edges * 4;
  int* edge_src = (int*)p;                   p += (size_t)n_edges * 4;
  // fallback-only arrays
  int* cnt = (int*)p;                        p += (size_t)n_nodes * 4;
  int* exs = (int*)p;                        p += (size_t)n_nodes * 4;
  int* bsum = (int*)p;                       p += (size_t)(nb + 1) * 4;
  int* cursor = (int*)p;                     p += (size_t)n_nodes * 4;

  sniff_kernel<<<1, 64, 0, stream>>>((const unsigned short*)h, flag);

  wt_kernel<<<384, 128, 0, stream>>>(Wq, Wk, Wv, Wt, flag);

  const int pgrid = (n_nodes + MT - 1) / MT;
  proj_kernel<<<pgrid, 256, 0, stream>>>(h, Wt, bq, bk, bv, Qf, Kb, Vb, flag,
                                         n_nodes);

  const int nchunk = (n_edges + CHUNK - 1) / CHUNK;
  if (n_nodes <= 65536) {
    hipMemsetAsync(bucket_size, 0, 258 * sizeof(int), stream);
    bucket_hist_kernel<<<nchunk, 256, 0, stream>>>(dst, bucket_size, n_edges);
    bucket_scan_kernel<<<1, 256, 0, stream>>>(bucket_size, bucket_base,
                                              bucket_cur, nbuck, n_edges);
    bucketize_kernel<<<nchunk, 256, 0, stream>>>(src, dst, bucket_cur, ebuf,
                                                 n_edges);
    bucket_csr_kernel<<<nbuck, 256, 0, stream>>>(ebuf, bucket_base, row_ptr,
                                                 edge_src, n_nodes, nbuck);
  } else {
    hipMemsetAsync(cnt, 0, (size_t)n_nodes * sizeof(int), stream);
    const int eb = 256;
    const int egrid = (n_edges + eb - 1) / eb;
    hist_kernel<<<egrid, eb, 0, stream>>>(dst, cnt, n_edges);
    scan1_kernel<<<nb, SCAN_B, 0, stream>>>(cnt, exs, bsum, n_nodes);
    scan2_kernel<<<1, SCAN_B, 0, stream>>>(bsum, nb);
    scan3_kernel<<<nb, SCAN_B, 0, stream>>>(exs, bsum, row_ptr, cursor,
                                            n_nodes, n_edges);
    scatter_kernel<<<egrid, eb, 0, stream>>>(src, dst, cursor, edge_src,
                                             n_edges);
  }

  gather_kernel<<<n_nodes, 128, 0, stream>>>(row_ptr, edge_src, Qf, Kb, Vb,
                                             d_out, flag, n_nodes);
}

// Round 8
// 318.738 us; speedup vs baseline: 3.8772x; 1.0660x over previous
//
#include <hip/hip_runtime.h>
#include <hip/hip_bf16.h>

#define IN_DIM 128
#define HH 8
#define DD 16
#define HD 128   // H*D
#define SCAN_B 256
#define CHUNK 8192  // edges per hist/bucketize block

#define MT  64   // nodes per proj block
#define KP  136  // padded K stride for Wt (bf16 elems)
#define NCH 128  // output-channel chunk staged in LDS

typedef float f32x4 __attribute__((ext_vector_type(4)));
typedef short s16x8 __attribute__((ext_vector_type(8)));

// ---------------------------------------------------------------------------
// dtype sniff helper: returns 1 if h is fp32 storage, 0 if bf16.
// Reads 64 even-indexed uint16s of h; bf16 values of N(0,1) have sane
// exponents ~always, fp32 low-mantissa halves ~12% of the time.
// ---------------------------------------------------------------------------
__device__ __forceinline__ int sniff_fp32(const unsigned short* h_raw) {
  int sane = 0;
#pragma unroll
  for (int i = 0; i < 128; i += 2) {
    const unsigned short u = h_raw[i];
    const int expo = (u >> 7) & 0xFF;
    if (expo >= 112 && expo <= 143) sane++;
  }
  return (sane >= 40) ? 0 : 1;
}

// ---------------------------------------------------------------------------
// Kernel 1: W^T staging (self-sniffing).  Wt[n][k] bf16, n in [0,384),
// padded stride KP.  Block 0 also publishes the global flag and zeroes
// bucket_size (so no sniff kernel / memset launch on the hot path).
// ---------------------------------------------------------------------------
__global__ __launch_bounds__(128) void wt_kernel(
    const unsigned short* __restrict__ h_raw,
    const void* __restrict__ Wq, const void* __restrict__ Wk,
    const void* __restrict__ Wv, __hip_bfloat16* __restrict__ Wt,
    int* __restrict__ flag, int* __restrict__ bucket_size) {
  const int isf = sniff_fp32(h_raw);  // block-uniform, ~64 L2-hit loads
  const int n = blockIdx.x;
  const int k = threadIdx.x;
  if (n == 0) {
    if (k == 0) *flag = isf;
    for (int j = k; j < 258; j += 128) bucket_size[j] = 0;
  }
  const int mat = n >> 7;
  const int col = n & 127;
  const void* W = (mat == 0) ? Wq : (mat == 1) ? Wk : Wv;
  float v;
  if (isf) v = ((const float*)W)[(size_t)k * HD + col];
  else     v = __bfloat162float(((const __hip_bfloat16*)W)[(size_t)k * HD + col]);
  Wt[(size_t)n * KP + k] = __float2bfloat16(v);
}

// ---------------------------------------------------------------------------
// Kernel 2 (fused): blocks [0,pgrid) = MFMA projection; blocks
// [pgrid, pgrid+nchunk) = bucket histogram (independent work, hidden under
// proj's MFMA time).  Hist role reuses proj's LDS allocation.
// ---------------------------------------------------------------------------
__global__ __launch_bounds__(256) void proj_hist_kernel(
    const void* __restrict__ h, const __hip_bfloat16* __restrict__ Wt,
    const void* __restrict__ bq, const void* __restrict__ bk,
    const void* __restrict__ bv,
    float* __restrict__ Qf, __hip_bfloat16* __restrict__ Kb,
    __hip_bfloat16* __restrict__ Vb,
    const int* __restrict__ flag, int n_nodes,
    const int* __restrict__ dst, int* __restrict__ bucket_size, int n_edges,
    int pgrid) {
  __shared__ short Bs[NCH * KP];
  __shared__ short As[MT * KP];

  const int tid = threadIdx.x;

  if (blockIdx.x >= pgrid) {
    // ---- bucket histogram role ----
    int* lh = (int*)Bs;
    const int e0 = (blockIdx.x - pgrid) * CHUNK;
    const int e1 = (e0 + CHUNK < n_edges) ? e0 + CHUNK : n_edges;
    lh[tid] = 0;
    __syncthreads();
    for (int e = e0 + tid; e < e1; e += 256) atomicAdd(&lh[dst[e] >> 8], 1);
    __syncthreads();
    if (lh[tid] > 0) atomicAdd(&bucket_size[tid], lh[tid]);
    return;
  }

  // ---- projection role ----
  const int node0 = blockIdx.x * MT;
  const int isf = *flag;

#pragma unroll
  for (int j = 0; j < 16; ++j) {
    const int pid = tid + j * 256;
    const int m = pid >> 6;
    const int kk = (pid & 63) * 2;
    const int g = node0 + m;
    unsigned int pack = 0;
    if (g < n_nodes) {
      if (isf) {
        const float2 f2 = *(const float2*)((const float*)h + (size_t)g * HD + kk);
        const __hip_bfloat16 b0 = __float2bfloat16(f2.x);
        const __hip_bfloat16 b1 = __float2bfloat16(f2.y);
        pack = (unsigned int)(*(const unsigned short*)&b0) |
               ((unsigned int)(*(const unsigned short*)&b1) << 16);
      } else {
        pack = *(const unsigned int*)((const __hip_bfloat16*)h +
                                      (size_t)g * HD + kk);
      }
    }
    *(unsigned int*)&As[m * KP + kk] = pack;
  }
  __syncthreads();

  const int wave = tid >> 6;
  const int lane = tid & 63;
  const int l15 = lane & 15;
  const int quad = lane >> 4;

  s16x8 afrag[4];
#pragma unroll
  for (int k4 = 0; k4 < 4; ++k4)
    afrag[k4] = *(const s16x8*)&As[(wave * 16 + l15) * KP + k4 * 32 + quad * 8];

  for (int c = 0; c < 3; ++c) {
    __syncthreads();
    const uint4* gsrc = (const uint4*)(Wt + (size_t)c * NCH * KP);
    for (int j = tid; j < (NCH * KP * 2) / 16; j += 256)
      ((uint4*)Bs)[j] = gsrc[j];
    __syncthreads();

    f32x4 acc[8];
#pragma unroll
    for (int t = 0; t < 8; ++t) acc[t] = (f32x4){0.f, 0.f, 0.f, 0.f};

#pragma unroll
    for (int t = 0; t < 8; ++t) {
#pragma unroll
      for (int k4 = 0; k4 < 4; ++k4) {
        const s16x8 bfrag =
            *(const s16x8*)&Bs[(t * 16 + l15) * KP + k4 * 32 + quad * 8];
        acc[t] = __builtin_amdgcn_mfma_f32_16x16x32_bf16(afrag[k4], bfrag,
                                                         acc[t], 0, 0, 0);
      }
    }

    const void* bp = (c == 0) ? bq : (c == 1) ? bk : bv;
#pragma unroll
    for (int t = 0; t < 8; ++t) {
      const int ncol = t * 16 + l15;
      const float bias = isf ? ((const float*)bp)[ncol]
                             : __bfloat162float(((const __hip_bfloat16*)bp)[ncol]);
#pragma unroll
      for (int r = 0; r < 4; ++r) {
        const int g = node0 + wave * 16 + quad * 4 + r;
        if (g < n_nodes) {
          const float val = acc[t][r] + bias;
          const size_t o = (size_t)g * HD + ncol;
          if (c == 0)      Qf[o] = val;
          else if (c == 1) Kb[o] = __float2bfloat16(val);
          else             Vb[o] = __float2bfloat16(val);
        }
      }
    }
  }
}

// ---------------------------------------------------------------------------
// Bucket scan: exclusive prefix over bucket sizes.
// ---------------------------------------------------------------------------
__global__ __launch_bounds__(256) void bucket_scan_kernel(
    const int* __restrict__ bucket_size, int* __restrict__ bucket_base,
    int* __restrict__ bucket_cur, int nbuck, int n_edges) {
  __shared__ int sh[256];
  const int t = threadIdx.x;
  const int v = (t < nbuck) ? bucket_size[t] : 0;
  sh[t] = v;
  __syncthreads();
  for (int off = 1; off < 256; off <<= 1) {
    int add = (t >= off) ? sh[t - off] : 0;
    __syncthreads();
    sh[t] += add;
    __syncthreads();
  }
  const int excl = sh[t] - v;
  if (t < nbuck) {
    bucket_base[t] = excl;
    bucket_cur[t] = excl;
  }
  if (t == 0) bucket_base[nbuck] = n_edges;
}

// Pass A: block-aggregated bucket scatter; writes land in ~contiguous runs.
__global__ __launch_bounds__(256) void bucketize_kernel(
    const int* __restrict__ src, const int* __restrict__ dst,
    int* __restrict__ bucket_cur, unsigned int* __restrict__ ebuf,
    int n_edges) {
  __shared__ int lh[256];
  const int t = threadIdx.x;
  const int e0 = blockIdx.x * CHUNK;
  const int e1 = (e0 + CHUNK < n_edges) ? e0 + CHUNK : n_edges;
  lh[t] = 0;
  __syncthreads();
  for (int e = e0 + t; e < e1; e += 256) atomicAdd(&lh[dst[e] >> 8], 1);
  __syncthreads();
  const int cnt_local = lh[t];
  int base = 0;
  if (cnt_local > 0) base = atomicAdd(&bucket_cur[t], cnt_local);
  __syncthreads();
  lh[t] = base;
  __syncthreads();
  for (int e = e0 + t; e < e1; e += 256) {
    const int d = dst[e];
    const int pos = atomicAdd(&lh[d >> 8], 1);
    ebuf[pos] = ((unsigned int)src[e] << 16) | (unsigned int)d;
  }
}

// Fused pass B: per-bucket count -> LDS scan -> row_ptr -> LDS-cursor scatter.
__global__ __launch_bounds__(256) void bucket_csr_kernel(
    const unsigned int* __restrict__ ebuf, const int* __restrict__ bucket_base,
    int* __restrict__ row_ptr, int* __restrict__ edge_src,
    int n_nodes, int nbuck) {
  __shared__ int lc[256];
  __shared__ int sh[256];
  const int b = blockIdx.x;
  const int t = threadIdx.x;
  const int lo = bucket_base[b], hi = bucket_base[b + 1];
  const int nbase = b << 8;

  lc[t] = 0;
  __syncthreads();
  for (int i = lo + t; i < hi; i += 256)
    atomicAdd(&lc[(ebuf[i] & 0xFFFFu) - nbase], 1);
  __syncthreads();

  const int v = lc[t];
  sh[t] = v;
  __syncthreads();
  for (int off = 1; off < 256; off <<= 1) {
    int add = (t >= off) ? sh[t - off] : 0;
    __syncthreads();
    sh[t] += add;
    __syncthreads();
  }
  const int excl = sh[t] - v;

  const int node = nbase + t;
  if (node < n_nodes) row_ptr[node] = lo + excl;
  if (b == nbuck - 1 && t == 255) row_ptr[n_nodes] = hi;

  __syncthreads();
  lc[t] = lo + excl;
  __syncthreads();
  for (int i = lo + t; i < hi; i += 256) {
    const unsigned int pkd = ebuf[i];
    const int pos = atomicAdd(&lc[(pkd & 0xFFFFu) - nbase], 1);
    edge_src[pos] = (int)(pkd >> 16);
  }
}

// ---------------------------------------------------------------------------
// Fallback CSR build (n_nodes > 65536): direct hist + scans + scatter.
// ---------------------------------------------------------------------------
__global__ __launch_bounds__(256) void hist_kernel(
    const int* __restrict__ dst, int* __restrict__ cnt, int n_edges) {
  const int e = blockIdx.x * blockDim.x + threadIdx.x;
  if (e < n_edges) atomicAdd(&cnt[dst[e]], 1);
}

__global__ __launch_bounds__(256) void scatter_kernel(
    const int* __restrict__ src, const int* __restrict__ dst,
    int* __restrict__ cursor, int* __restrict__ edge_src, int n_edges) {
  const int e = blockIdx.x * blockDim.x + threadIdx.x;
  if (e < n_edges) {
    const int pos = atomicAdd(&cursor[dst[e]], 1);
    edge_src[pos] = src[e];
  }
}

__global__ __launch_bounds__(SCAN_B) void scan1_kernel(
    const int* __restrict__ cnt, int* __restrict__ exs,
    int* __restrict__ bsum, int n) {
  __shared__ int sh[SCAN_B];
  const int t = threadIdx.x;
  const int i = blockIdx.x * SCAN_B + t;
  int v = (i < n) ? cnt[i] : 0;
  sh[t] = v;
  __syncthreads();
  for (int off = 1; off < SCAN_B; off <<= 1) {
    int add = (t >= off) ? sh[t - off] : 0;
    __syncthreads();
    sh[t] += add;
    __syncthreads();
  }
  if (i < n) exs[i] = sh[t] - v;
  if (t == SCAN_B - 1) bsum[blockIdx.x] = sh[t];
}

__global__ __launch_bounds__(SCAN_B) void scan2_kernel(int* __restrict__ bsum,
                                                       int nb) {
  __shared__ int sh[SCAN_B];
  const int t = threadIdx.x;
  if (nb <= SCAN_B) {
    int v = (t < nb) ? bsum[t] : 0;
    sh[t] = v;
    __syncthreads();
    for (int off = 1; off < SCAN_B; off <<= 1) {
      int add = (t >= off) ? sh[t - off] : 0;
      __syncthreads();
      sh[t] += add;
      __syncthreads();
    }
    if (t < nb) bsum[t] = sh[t] - v;
  } else if (t == 0) {
    int run = 0;
    for (int b = 0; b < nb; ++b) { int v = bsum[b]; bsum[b] = run; run += v; }
  }
}

__global__ __launch_bounds__(SCAN_B) void scan3_kernel(
    const int* __restrict__ exs, const int* __restrict__ bsum,
    int* __restrict__ row_ptr, int* __restrict__ cursor, int n, int n_edges) {
  const int i = blockIdx.x * SCAN_B + threadIdx.x;
  if (i < n) {
    const int v = exs[i] + bsum[blockIdx.x];
    row_ptr[i] = v;
    cursor[i] = v;
  }
  if (i == 0) row_ptr[n] = n_edges;
}

// ---------------------------------------------------------------------------
// Kernel 3: per-destination gather, two-phase per 16-edge group (round-6
// V layout, refined):
//   Score stage: thread = (edge 0..15, head 0..7); K row 2x16B loads, one
//     exp per (edge,head); packs (score, src) into ONE float2 LDS slot and
//     accumulates z locally (removed from the V loop).
//   V stage: thread = channel; per edge ONE ds_read_b64 (score+src), one
//     bf16 V load, one FMA.
// ---------------------------------------------------------------------------
__global__ __launch_bounds__(128) void gather_kernel(
    const int* __restrict__ row_ptr, const int* __restrict__ edge_src,
    const float* __restrict__ Qf, const __hip_bfloat16* __restrict__ Kb,
    const __hip_bfloat16* __restrict__ Vb,
    void* __restrict__ out, const int* __restrict__ flag, int n_nodes) {
  __shared__ float2 sc[2][16 * HH];  // (score, src-bits) per (edge, head)
  __shared__ float zred[16 * HH];    // final z reduction

  const int d = blockIdx.x;
  const int tid = threadIdx.x;

  const int eloc = tid >> 3;   // score stage: edge slot
  const int hh8  = tid & 7;    // score stage: head
  const int hd16 = tid >> 4;   // V stage: head of channel tid

  const int start = row_ptr[d];
  const int deg = row_ptr[d + 1] - start;

  float qreg[16];
  {
    const f32x4* qp = (const f32x4*)(Qf + (size_t)d * HD + hh8 * 16);
#pragma unroll
    for (int j = 0; j < 4; ++j) {
      const f32x4 q4 = qp[j];
      qreg[j * 4 + 0] = q4[0] * 0.25f;
      qreg[j * 4 + 1] = q4[1] * 0.25f;
      qreg[j * 4 + 2] = q4[2] * 0.25f;
      qreg[j * 4 + 3] = q4[3] * 0.25f;
    }
  }

  float accV = 0.0f;   // V-stage accumulator (channel tid)
  float zacc = 0.0f;   // score-stage z accumulator (edge slot eloc, head hh8)
  const int ngroups = (deg + 15) >> 4;

  for (int g = 0; g < ngroups; ++g) {
    const int buf = g & 1;
    const int ei = g * 16 + eloc;

    float score = 0.0f;
    int s = 0;
    if (ei < deg) {
      s = edge_src[start + ei];
      const uint4* kp = (const uint4*)(Kb + (size_t)s * HD + hh8 * 16);
      unsigned int kw[8];
      *(uint4*)&kw[0] = kp[0];
      *(uint4*)&kw[4] = kp[1];
      float dot = 0.0f;
#pragma unroll
      for (int i = 0; i < 8; ++i) {
        const float klo = __uint_as_float(kw[i] << 16);
        const float khi = __uint_as_float(kw[i] & 0xFFFF0000u);
        dot = fmaf(qreg[2 * i], klo, dot);
        dot = fmaf(qreg[2 * i + 1], khi, dot);
      }
      score = __expf(fminf(fmaxf(dot, -5.0f), 5.0f));
    }
    zacc += score;
    sc[buf][eloc * HH + hh8] = make_float2(score, __int_as_float(s));
    __syncthreads();

    const int rem = deg - g * 16;
    const int lim = (rem < 16) ? rem : 16;
    if (lim == 16) {
#pragma unroll
      for (int e = 0; e < 16; ++e) {
        const float2 pe = sc[buf][e * HH + hd16];
        const int s2 = __float_as_int(pe.y);
        const unsigned short vu =
            *(const unsigned short*)(Vb + (size_t)s2 * HD + tid);
        accV = fmaf(pe.x, __uint_as_float(((unsigned int)vu) << 16), accV);
      }
    } else {
      for (int e = 0; e < lim; ++e) {
        const float2 pe = sc[buf][e * HH + hd16];
        const int s2 = __float_as_int(pe.y);
        const unsigned short vu =
            *(const unsigned short*)(Vb + (size_t)s2 * HD + tid);
        accV = fmaf(pe.x, __uint_as_float(((unsigned int)vu) << 16), accV);
      }
    }
  }

  // z: reduce the 16 edge-slot partials per head
  zred[eloc * HH + hh8] = zacc;
  __syncthreads();
  float aZ = 0.0f;
#pragma unroll
  for (int i = 0; i < 16; ++i) aZ += zred[i * HH + hd16];

  const float r = accV / (aZ + 1e-6f);
  const size_t o = (size_t)d * HD + tid;
  if (*flag) ((float*)out)[o] = r;
  else       ((__hip_bfloat16*)out)[o] = __float2bfloat16(r);
}

// ---------------------------------------------------------------------------
extern "C" void kernel_launch(void* const* d_in, const int* in_sizes, int n_in,
                              void* d_out, int out_size, void* d_ws, size_t ws_size,
                              hipStream_t stream) {
  const void* h  = d_in[0];
  const void* Wq = d_in[1];
  const void* bq = d_in[2];
  const void* Wk = d_in[3];
  const void* bk = d_in[4];
  const void* Wv = d_in[5];
  const void* bv = d_in[6];
  const int* src = (const int*)d_in[7];
  const int* dst = (const int*)d_in[8];

  const int n_nodes = in_sizes[0] / IN_DIM;  // 50000
  const int n_edges = in_sizes[7];           // 1600000
  const int nb = (n_nodes + SCAN_B - 1) / SCAN_B;
  const int nbuck = (n_nodes + 255) >> 8;

  // workspace layout (256B-aligned chunks)
  char* p = (char*)d_ws;
  int* flag = (int*)p;                       p += 256;
  float* Qf = (float*)p;                     p += (size_t)n_nodes * HD * 4;
  __hip_bfloat16* Kb = (__hip_bfloat16*)p;   p += (size_t)n_nodes * HD * 2;
  __hip_bfloat16* Vb = (__hip_bfloat16*)p;   p += (size_t)n_nodes * HD * 2;
  __hip_bfloat16* Wt = (__hip_bfloat16*)p;   p += ((size_t)384 * KP * 2 + 255) / 256 * 256;
  int* bucket_size = (int*)p;                p += 258 * 4;
  int* bucket_base = (int*)p;                p += 258 * 4;
  int* bucket_cur = (int*)p;                 p += 258 * 4;
  int* row_ptr = (int*)p;                    p += (size_t)(n_nodes + 1) * 4;
  unsigned int* ebuf = (unsigned int*)p;     p += (size_t)n_edges * 4;
  int* edge_src = (int*)p;                   p += (size_t)n_edges * 4;
  // fallback-only arrays
  int* cnt = (int*)p;                        p += (size_t)n_nodes * 4;
  int* exs = (int*)p;                        p += (size_t)n_nodes * 4;
  int* bsum = (int*)p;                       p += (size_t)(nb + 1) * 4;
  int* cursor = (int*)p;                     p += (size_t)n_nodes * 4;

  // wt: self-sniffs, publishes flag, zeroes bucket_size
  wt_kernel<<<384, 128, 0, stream>>>((const unsigned short*)h, Wq, Wk, Wv, Wt,
                                     flag, bucket_size);

  const int pgrid = (n_nodes + MT - 1) / MT;
  const int nchunk = (n_edges + CHUNK - 1) / CHUNK;

  if (n_nodes <= 65536) {
    // fused proj + bucket-hist
    proj_hist_kernel<<<pgrid + nchunk, 256, 0, stream>>>(
        h, Wt, bq, bk, bv, Qf, Kb, Vb, flag, n_nodes, dst, bucket_size,
        n_edges, pgrid);
    bucket_scan_kernel<<<1, 256, 0, stream>>>(bucket_size, bucket_base,
                                              bucket_cur, nbuck, n_edges);
    bucketize_kernel<<<nchunk, 256, 0, stream>>>(src, dst, bucket_cur, ebuf,
                                                 n_edges);
    bucket_csr_kernel<<<nbuck, 256, 0, stream>>>(ebuf, bucket_base, row_ptr,
                                                 edge_src, n_nodes, nbuck);
  } else {
    // fallback: proj alone, then direct hist + scans + scatter
    proj_hist_kernel<<<pgrid, 256, 0, stream>>>(
        h, Wt, bq, bk, bv, Qf, Kb, Vb, flag, n_nodes, dst, bucket_size,
        n_edges, pgrid);
    hipMemsetAsync(cnt, 0, (size_t)n_nodes * sizeof(int), stream);
    const int eb = 256;
    const int egrid = (n_edges + eb - 1) / eb;
    hist_kernel<<<egrid, eb, 0, stream>>>(dst, cnt, n_edges);
    scan1_kernel<<<nb, SCAN_B, 0, stream>>>(cnt, exs, bsum, n_nodes);
    scan2_kernel<<<1, SCAN_B, 0, stream>>>(bsum, nb);
    scan3_kernel<<<nb, SCAN_B, 0, stream>>>(exs, bsum, row_ptr, cursor,
                                            n_nodes, n_edges);
    scatter_kernel<<<egrid, eb, 0, stream>>>(src, dst, cursor, edge_src,
                                             n_edges);
  }

  gather_kernel<<<n_nodes, 128, 0, stream>>>(row_ptr, edge_src, Qf, Kb, Vb,
                                             d_out, flag, n_nodes);
}